// Round 11
// baseline (121.002 us; speedup 1.0000x reference)
//
#include <hip/hip_runtime.h>
#include <hip/hip_bf16.h>
#include <math.h>

// DirectVoxGO fused forward, v11.
// = v9 structure (proven 44.4us mlp) with occupancy caps raised:
//   mlp launch_bounds(256,5): 5 blocks/CU (LDS 32KB x5 = 160KB exact), 20 waves/CU.
//   gather launch_bounds(256,8).
// v10's w2-LDS staging REVERTED (it halved occupancy: 44->55us; latency-bound
// kernel scales with waves-in-flight, not with L2 traffic).

typedef __bf16 bf16x4 __attribute__((ext_vector_type(4)));
typedef __bf16 bf16x8 __attribute__((ext_vector_type(8)));
typedef float  f32x4  __attribute__((ext_vector_type(4)));

#define ACT_SHIFT_F (-13.815509557964774f)

// ---- full-path ws layout (bytes) ----
#define B1R_B   45056
#define PACK2_B 2142208
#define FEAT2_B 34142208
#define NEED_FULL 46725120ull

// ---- fallback ws layout (old, unchanged) ----
#define EMB_B   53248
#define PACK_B  315392
#define NEED_PACK 32315392ull

// ================= prep2 (full path) =================
__global__ __launch_bounds__(256)
void dvgo_prep2(const float* __restrict__ g_gd, const float* __restrict__ g_gc,
                const float* __restrict__ g_w1, const float* __restrict__ g_w2,
                const float* __restrict__ g_w3, const float* __restrict__ g_dir,
                const float* __restrict__ g_b1,
                bf16x8* __restrict__ pack, __bf16* __restrict__ wsb,
                float* __restrict__ b1r)
{
    const int bid = blockIdx.x;
    const int tid = threadIdx.x;
    if (bid < 3907) {
        const int gi = bid * 256 + tid;
        if (gi >= 1000000) return;
        bf16x8 v0, v1;
        #pragma unroll
        for (int c = 0; c < 8; ++c) v0[c] = (__bf16)g_gc[c * 1000000 + gi];
        #pragma unroll
        for (int c = 0; c < 4; ++c) v1[c] = (__bf16)g_gc[(8 + c) * 1000000 + gi];
        v1[4] = (__bf16)g_gd[gi];
        v1[5] = (__bf16)0.0f; v1[6] = (__bf16)0.0f; v1[7] = (__bf16)0.0f;
        pack[gi * 2 + 0] = v0;
        pack[gi * 2 + 1] = v1;
        return;
    }
    const int idx2 = bid - 3907;
    if (idx2 < 88) {
        const int idx = idx2 * 256 + tid;
        if (idx < 4096) {                       // w1 A-frags, K=32, k>=12 zero
            const int j = idx & 7, lane = (idx >> 3) & 63, ct = idx >> 9;
            const int n = ct * 16 + (lane & 15);
            const int k = ((lane >> 4) & 3) * 8 + j;
            wsb[idx] = (__bf16)((k < 12) ? g_w1[k * 128 + n] : 0.0f);
        } else if (idx < 20480) {               // w2 A-frags
            const int i2 = idx - 4096;
            const int j = i2 & 7, lane = (i2 >> 3) & 63, ks = (i2 >> 9) & 3, ct = i2 >> 11;
            const int n = ct * 16 + (lane & 15);
            const int k = ks * 32 + ((lane >> 4) & 3) * 8 + j;
            wsb[idx] = (__bf16)g_w2[k * 128 + n];
        } else if (idx < 22528) {               // w3 A-frags, cols >=3 zero
            const int i3 = idx - 20480;
            const int j = i3 & 7, lane = (i3 >> 3) & 63, ks = i3 >> 9;
            const int c = lane & 15;
            const int k = ks * 32 + ((lane >> 4) & 3) * 8 + j;
            wsb[idx] = (__bf16)((c < 3) ? g_w3[k * 3 + c] : 0.0f);
        }
        return;
    }
    // b1r: b1 + emb27 . w1[12:39,:]
    const int rr  = idx2 - 88;
    const int ray = rr * 2 + (tid >> 7);
    const int n   = tid & 127;
    const float d0 = g_dir[ray*3+0], d1 = g_dir[ray*3+1], d2 = g_dir[ray*3+2];
    float s = g_b1[n];
    s += d0 * g_w1[12*128 + n] + d1 * g_w1[13*128 + n] + d2 * g_w1[14*128 + n];
    #pragma unroll
    for (int m = 0; m < 12; ++m) {
        const int i = m >> 2, j = m & 3;
        const float di = (i == 0) ? d0 : ((i == 1) ? d1 : d2);
        const float a = di * (float)(1 << j);
        s += sinf(a) * g_w1[(15 + m)*128 + n];
        s += cosf(a) * g_w1[(27 + m)*128 + n];
    }
    b1r[ray*128 + n] = s;
}

// ================= G: gather, 1 thread/point =================
__global__ __launch_bounds__(256, 8)
void dvgo_gather(const float* __restrict__ g_org, const float* __restrict__ g_dir,
                 const float* __restrict__ g_len, const bf16x8* __restrict__ pack,
                 __bf16* __restrict__ feat, float* __restrict__ out_alpha)
{
    const int pt  = blockIdx.x * 256 + threadIdx.x;
    const int ray = pt >> 7;
    const float d0 = g_dir[ray*3+0], d1 = g_dir[ray*3+1], d2 = g_dir[ray*3+2];
    const float o0 = g_org[ray*3+0], o1 = g_org[ray*3+1], o2 = g_org[ray*3+2];
    const float len = g_len[pt];

    const float px = (o0 + d0*len + 1.0f) * 49.5f;
    const float py = (o1 + d1*len + 1.0f) * 49.5f;
    const float pz = (o2 + d2*len + 1.0f) * 49.5f;
    const float fx = floorf(px), fy = floorf(py), fz = floorf(pz);
    const int ix = (int)fx, iy = (int)fy, iz = (int)fz;
    const float qx = px - fx, qy = py - fy, qz = pz - fz;
    const float wxa[2] = {1.0f - qx, qx};
    const float wya[2] = {1.0f - qy, qy};
    const float wza[2] = {1.0f - qz, qz};
    const int  cxa[2] = {min(max(ix,0),99),   min(max(ix+1,0),99)};
    const int  cya[2] = {min(max(iy,0),99),   min(max(iy+1,0),99)};
    const int  cza[2] = {min(max(iz,0),99),   min(max(iz+1,0),99)};
    const bool vxa[2] = {(unsigned)ix < 100u, (unsigned)(ix+1) < 100u};
    const bool vya[2] = {(unsigned)iy < 100u, (unsigned)(iy+1) < 100u};
    const bool vza[2] = {(unsigned)iz < 100u, (unsigned)(iz+1) < 100u};

    float den = 0.0f;
    float cc[12];
    #pragma unroll
    for (int c = 0; c < 12; ++c) cc[c] = 0.0f;

    #pragma unroll
    for (int dz = 0; dz < 2; ++dz)
    #pragma unroll
    for (int dy = 0; dy < 2; ++dy)
    #pragma unroll
    for (int dx = 0; dx < 2; ++dx) {
        float w = wxa[dx] * wya[dy] * wza[dz];
        if (!(vxa[dx] && vya[dy] && vza[dz])) w = 0.0f;
        const int gi = (cza[dz]*100 + cya[dy])*100 + cxa[dx];
        const bf16x8 v0 = pack[gi*2 + 0];
        const bf16x8 v1 = pack[gi*2 + 1];
        #pragma unroll
        for (int c = 0; c < 8; ++c) cc[c]     += w * (float)v0[c];
        #pragma unroll
        for (int c = 0; c < 4; ++c) cc[8 + c] += w * (float)v1[c];
        den += w * (float)v1[4];
    }

    const float interval = sqrtf(d0*d0 + d1*d1 + d2*d2);
    const float e = expf(den + ACT_SHIFT_F);
    out_alpha[pt] = -expm1f(-interval * log1pf(e));

    bf16x8 f0; bf16x4 f1;
    #pragma unroll
    for (int c = 0; c < 8; ++c) f0[c] = (__bf16)cc[c];
    #pragma unroll
    for (int c = 0; c < 4; ++c) f1[c] = (__bf16)cc[8 + c];
    __bf16* fo = feat + (size_t)pt * 12;
    *(bf16x8*)(fo) = f0;
    *(bf16x4*)(fo + 8) = f1;
}

// ================= M: MLP v11 (= v9, one barrier, launch_bounds(256,5)) =================
__global__ __launch_bounds__(256, 5)
void dvgo_mlp(const bf16x8* __restrict__ wf, const float* __restrict__ b1r,
              const __bf16* __restrict__ feat,
              const float* __restrict__ g_b2, const float* __restrict__ g_b3,
              float* __restrict__ out_rgb)
{
    __shared__ __align__(16) char smem[32768];   // h[pt=128][n=128] bf16, swizzled
    const int tid  = threadIdx.x;
    const int ray  = blockIdx.x;
    const int lane = tid & 63;
    const int wid  = tid >> 6;
    const int lr   = lane & 15;
    const int lk   = lane >> 4;
    const int sz   = (lr & 7) << 4;

    int wb1[2];
    #pragma unroll
    for (int c2 = 0; c2 < 2; ++c2)
        wb1[c2] = lr*256 + ((((wid*2 + c2)*32) + lk*8) ^ sz);
    int rb2[4];
    #pragma unroll
    for (int ks = 0; ks < 4; ++ks)
        rb2[ks] = (wid*32 + lr)*256 + ((ks*64 + lk*16) ^ sz);
    const int rowb = (wid*32 + lr)*256;

    bf16x8 zed;
    #pragma unroll
    for (int j = 0; j < 8; ++j) zed[j] = (__bf16)0.0f;

    // ---- GEMM1 (slice-N), K=32, two 64-pt passes; acc 32 regs ----
    bf16x8 aw1[2];
    #pragma unroll
    for (int c2 = 0; c2 < 2; ++c2)
        aw1[c2] = wf[(wid*2 + c2)*64 + lane];

    #pragma unroll
    for (int h = 0; h < 2; ++h) {
        bf16x8 bb[4];
        #pragma unroll
        for (int r4 = 0; r4 < 4; ++r4) {
            const int pt = ray*128 + (h*4 + r4)*16 + lr;
            const bf16x8 t0 = *(const bf16x8*)(feat + (size_t)pt*12);
            const bf16x4 t1 = *(const bf16x4*)(feat + (size_t)pt*12 + 8);
            bf16x8 tl;
            #pragma unroll
            for (int j = 0; j < 4; ++j) tl[j] = t1[j];
            #pragma unroll
            for (int j = 4; j < 8; ++j) tl[j] = (__bf16)0.0f;
            bb[r4] = (lk == 0) ? t0 : ((lk == 1) ? tl : zed);
        }
        f32x4 acc1[4][2];
        #pragma unroll
        for (int r4 = 0; r4 < 4; ++r4)
            #pragma unroll
            for (int c2 = 0; c2 < 2; ++c2) acc1[r4][c2] = (f32x4){0.f,0.f,0.f,0.f};
        #pragma unroll
        for (int r4 = 0; r4 < 4; ++r4)
            #pragma unroll
            for (int c2 = 0; c2 < 2; ++c2)
                acc1[r4][c2] = __builtin_amdgcn_mfma_f32_16x16x32_bf16(aw1[c2], bb[r4], acc1[r4][c2], 0, 0, 0);
        #pragma unroll
        for (int c2 = 0; c2 < 2; ++c2) {
            const f32x4 b1v = *(const f32x4*)(b1r + ray*128 + (wid*2 + c2)*16 + lk*4);
            #pragma unroll
            for (int r4 = 0; r4 < 4; ++r4) {
                bf16x4 hv;
                #pragma unroll
                for (int r = 0; r < 4; ++r)
                    hv[r] = (__bf16)fmaxf(acc1[r4][c2][r] + b1v[r], 0.0f);
                *(bf16x4*)(smem + wb1[c2] + (h*4 + r4)*4096) = hv;
            }
        }
    }
    __syncthreads();   // B1: h1 complete (the ONLY barrier)

    // ---- GEMM2 (pt-slice): own 32 pts x all 128 n2; per-ct acc = 8 regs ----
    bf16x8 hq[2][4];
    #pragma unroll
    for (int q = 0; q < 2; ++q)
        #pragma unroll
        for (int ks = 0; ks < 4; ++ks)
            hq[q][ks] = *(const bf16x8*)(smem + rb2[ks] + q*4096);

    #pragma unroll
    for (int ct = 0; ct < 8; ++ct) {
        bf16x8 aw2[4];
        #pragma unroll
        for (int ks = 0; ks < 4; ++ks)
            aw2[ks] = wf[512 + (ct*4 + ks)*64 + lane];
        f32x4 a0 = (f32x4){0.f,0.f,0.f,0.f};
        f32x4 a1 = (f32x4){0.f,0.f,0.f,0.f};
        #pragma unroll
        for (int ks = 0; ks < 4; ++ks) {
            a0 = __builtin_amdgcn_mfma_f32_16x16x32_bf16(aw2[ks], hq[0][ks], a0, 0, 0, 0);
            a1 = __builtin_amdgcn_mfma_f32_16x16x32_bf16(aw2[ks], hq[1][ks], a1, 0, 0, 0);
        }
        const f32x4 b2v = *(const f32x4*)(g_b2 + ct*16 + lk*4);
        bf16x4 h0, h1;
        #pragma unroll
        for (int r = 0; r < 4; ++r) {
            h0[r] = (__bf16)fmaxf(a0[r] + b2v[r], 0.0f);
            h1[r] = (__bf16)fmaxf(a1[r] + b2v[r], 0.0f);
        }
        const int csw = (ct*32 + lk*8) ^ sz;
        *(bf16x4*)(smem + rowb + csw) = h0;
        *(bf16x4*)(smem + rowb + 4096 + csw) = h1;
    }

    // ---- GEMM3: own 2 pt-tiles, w3 padded to 16 cols ----
    bf16x8 aw3[4];
    #pragma unroll
    for (int ks = 0; ks < 4; ++ks) aw3[ks] = wf[2560 + ks*64 + lane];
    f32x4 acc3[2];
    acc3[0] = (f32x4){0.f,0.f,0.f,0.f};
    acc3[1] = (f32x4){0.f,0.f,0.f,0.f};
    #pragma unroll
    for (int q = 0; q < 2; ++q)
        #pragma unroll
        for (int ks = 0; ks < 4; ++ks) {
            const bf16x8 hq3 = *(const bf16x8*)(smem + rb2[ks] + q*4096);
            acc3[q] = __builtin_amdgcn_mfma_f32_16x16x32_bf16(aw3[ks], hq3, acc3[q], 0, 0, 0);
        }

    // ---- sigmoid -> wave-private LDS staging -> coalesced store ----
    float* smf = (float*)(smem + wid*8192);
    if (lk == 0) {
        const float b30 = g_b3[0], b31 = g_b3[1], b32 = g_b3[2];
        #pragma unroll
        for (int q = 0; q < 2; ++q) {
            const int o = (q*16 + lr)*3;
            smf[o + 0] = 1.0f / (1.0f + __expf(-(acc3[q][0] + b30)));
            smf[o + 1] = 1.0f / (1.0f + __expf(-(acc3[q][1] + b31)));
            smf[o + 2] = 1.0f / (1.0f + __expf(-(acc3[q][2] + b32)));
        }
    }
    asm volatile("s_waitcnt lgkmcnt(0)");
    __builtin_amdgcn_sched_barrier(0);
    {
        const int base = (ray*128 + wid*32)*3;
        out_rgb[base + lane] = smf[lane];
        if (lane < 32) out_rgb[base + 64 + lane] = smf[64 + lane];
    }
}

// ================= fallback prep (old layout) + fused kernel (v3) =================
__global__ __launch_bounds__(256)
void dvgo_prep_fb(const float* __restrict__ g_gd, const float* __restrict__ g_gc,
                  const float* __restrict__ g_w1, const float* __restrict__ g_w2,
                  const float* __restrict__ g_w3, const float* __restrict__ g_dir,
                  bf16x8* __restrict__ pack, __bf16* __restrict__ wsb, int wbase)
{
    const int bid = blockIdx.x;
    if (bid < wbase) {
        const int gi = bid * 256 + threadIdx.x;
        if (gi >= 1000000) return;
        bf16x8 v0, v1;
        #pragma unroll
        for (int c = 0; c < 8; ++c) v0[c] = (__bf16)g_gc[c * 1000000 + gi];
        #pragma unroll
        for (int c = 0; c < 4; ++c) v1[c] = (__bf16)g_gc[(8 + c) * 1000000 + gi];
        v1[4] = (__bf16)g_gd[gi];
        v1[5] = (__bf16)0.0f; v1[6] = (__bf16)0.0f; v1[7] = (__bf16)0.0f;
        pack[gi * 2 + 0] = v0;
        pack[gi * 2 + 1] = v1;
        return;
    }
    const int idx = (bid - wbase) * 256 + threadIdx.x;
    if (idx < 8192) {
        const int j = idx & 7, lane = (idx >> 3) & 63, ks = (idx >> 9) & 1, ct = idx >> 10;
        const int n = ct * 16 + (lane & 15);
        const int k = ks * 32 + ((lane >> 4) & 3) * 8 + j;
        wsb[idx] = (__bf16)((k < 39) ? g_w1[k * 128 + n] : 0.0f);
    } else if (idx < 24576) {
        const int i2 = idx - 8192;
        const int j = i2 & 7, lane = (i2 >> 3) & 63, ks = (i2 >> 9) & 3, ct = i2 >> 11;
        const int n = ct * 16 + (lane & 15);
        const int k = ks * 32 + ((lane >> 4) & 3) * 8 + j;
        wsb[idx] = (__bf16)g_w2[k * 128 + n];
    }
}

#define FB_FEAT_OFF 0
#define FB_PCC_OFF  16384
#define FB_H1_OFF   0
#define FB_PRGB_OFF 0

template <bool PACKED>
__global__ __launch_bounds__(256, 4)
void dvgo_main(const float* __restrict__ g_org, const float* __restrict__ g_dir,
               const float* __restrict__ g_len, const float* __restrict__ g_gd,
               const float* __restrict__ g_gc, const float* __restrict__ g_b1,
               const float* __restrict__ g_b2, const float* __restrict__ g_w3,
               const float* __restrict__ g_b3, const bf16x8* __restrict__ wf,
               const bf16x8* __restrict__ g_pack,
               float* __restrict__ out_alpha, float* __restrict__ out_rgb)
{
    __shared__ __align__(16) char smem[32768];
    float* smf = (float*)smem;
    const int tid = threadIdx.x;
    const int ray = blockIdx.x;
    const float d0 = g_dir[ray*3+0], d1 = g_dir[ray*3+1], d2 = g_dir[ray*3+2];
    {
        const float o0 = g_org[ray*3+0], o1 = g_org[ray*3+1], o2 = g_org[ray*3+2];
        const int p = tid & 127;
        const int dzv = tid >> 7;
        const float len = g_len[ray*128 + p];
        const float px = (o0 + d0*len + 1.0f) * 49.5f;
        const float py = (o1 + d1*len + 1.0f) * 49.5f;
        const float pz = (o2 + d2*len + 1.0f) * 49.5f;
        const float fx = floorf(px), fy = floorf(py), fz = floorf(pz);
        const int ix = (int)fx, iy = (int)fy, iz0 = (int)fz;
        const float qx = px - fx, qy = py - fy, qz = pz - fz;
        const float wxa[2] = {1.0f - qx, qx};
        const float wya[2] = {1.0f - qy, qy};
        const int  cxa[2] = {min(max(ix,0),99),   min(max(ix+1,0),99)};
        const int  cya[2] = {min(max(iy,0),99),   min(max(iy+1,0),99)};
        const bool vxa[2] = {(unsigned)ix < 100u, (unsigned)(ix+1) < 100u};
        const bool vya[2] = {(unsigned)iy < 100u, (unsigned)(iy+1) < 100u};
        const int  iz = iz0 + dzv;
        const float wz = dzv ? qz : (1.0f - qz);
        const int  cz = min(max(iz,0),99);
        const bool vz = (unsigned)iz < 100u;
        float den = 0.0f;
        float cc[12];
        #pragma unroll
        for (int c = 0; c < 12; ++c) cc[c] = 0.0f;
        #pragma unroll
        for (int dy = 0; dy < 2; ++dy)
        #pragma unroll
        for (int dx = 0; dx < 2; ++dx) {
            float w = wxa[dx] * wya[dy] * wz;
            if (!(vxa[dx] && vya[dy] && vz)) w = 0.0f;
            const int gi = (cz*100 + cya[dy])*100 + cxa[dx];
            if (PACKED) {
                const bf16x8 v0 = g_pack[gi*2 + 0];
                const bf16x8 v1 = g_pack[gi*2 + 1];
                #pragma unroll
                for (int c = 0; c < 8; ++c) cc[c]     += w * (float)v0[c];
                #pragma unroll
                for (int c = 0; c < 4; ++c) cc[8 + c] += w * (float)v1[c];
                den += w * (float)v1[4];
            } else {
                den += w * g_gd[gi];
                #pragma unroll
                for (int c = 0; c < 12; ++c) cc[c] += w * g_gc[c*1000000 + gi];
            }
        }
        if (dzv) {
            #pragma unroll
            for (int c = 0; c < 12; ++c) smf[FB_PCC_OFF/4 + p*13 + c] = cc[c];
            smf[FB_PCC_OFF/4 + p*13 + 12] = den;
        }
        __syncthreads();
        if (!dzv) {
            #pragma unroll
            for (int c = 0; c < 12; ++c) cc[c] += smf[FB_PCC_OFF/4 + p*13 + c];
            den += smf[FB_PCC_OFF/4 + p*13 + 12];
            const float interval = sqrtf(d0*d0 + d1*d1 + d2*d2);
            const float e = expf(den + ACT_SHIFT_F);
            out_alpha[ray*128 + p] = -expm1f(-interval * log1pf(e));
            bf16x8 f0; bf16x4 f1;
            #pragma unroll
            for (int c = 0; c < 8; ++c) f0[c] = (__bf16)cc[c];
            #pragma unroll
            for (int c = 0; c < 4; ++c) f1[c] = (__bf16)cc[8+c];
            const int swz = (p & 7) << 4;
            *reinterpret_cast<bf16x8*>(smem + ((FB_FEAT_OFF + p*128 +  0) ^ swz)) = f0;
            *reinterpret_cast<bf16x4*>(smem + ((FB_FEAT_OFF + p*128 + 16) ^ swz)) = f1;
        } else {
            float vals[52];
            vals[0] = d0; vals[1] = d1; vals[2] = d2;
            #pragma unroll
            for (int i = 0; i < 3; ++i) {
                const float di = (i == 0) ? d0 : ((i == 1) ? d1 : d2);
                #pragma unroll
                for (int j = 0; j < 4; ++j) {
                    const float a = di * (float)(1 << j);
                    vals[3  + i*4 + j] = sinf(a);
                    vals[15 + i*4 + j] = cosf(a);
                }
            }
            #pragma unroll
            for (int c = 27; c < 52; ++c) vals[c] = 0.0f;
            const int swz = (p & 7) << 4;
            #pragma unroll
            for (int i = 0; i < 13; ++i) {
                bf16x4 v4;
                #pragma unroll
                for (int r = 0; r < 4; ++r) v4[r] = (__bf16)vals[i*4 + r];
                *reinterpret_cast<bf16x4*>(smem + ((FB_FEAT_OFF + p*128 + 24 + i*8) ^ swz)) = v4;
            }
        }
    }
    __syncthreads();
    const int lane = tid & 63;
    const int wid  = tid >> 6;
    const int lr   = lane & 15;
    const int lk   = lane >> 4;
    {
        bf16x8 bf[2][2];
        #pragma unroll
        for (int rt = 0; rt < 2; ++rt)
            #pragma unroll
            for (int ks = 0; ks < 2; ++ks) {
                const int pt = wid*32 + rt*16 + lr;
                int a = FB_FEAT_OFF + pt*128 + ks*64 + lk*16; a ^= (pt & 7) << 4;
                bf[rt][ks] = *reinterpret_cast<const bf16x8*>(smem + a);
            }
        __syncthreads();
        f32x4 acc1[2][8];
        #pragma unroll
        for (int rt = 0; rt < 2; ++rt)
            #pragma unroll
            for (int ct = 0; ct < 8; ++ct) acc1[rt][ct] = (f32x4){0.f,0.f,0.f,0.f};
        #pragma unroll
        for (int ct = 0; ct < 8; ++ct) {
            const bf16x8 aw0 = wf[(ct*2 + 0)*64 + lane];
            const bf16x8 aw1 = wf[(ct*2 + 1)*64 + lane];
            #pragma unroll
            for (int rt = 0; rt < 2; ++rt) {
                acc1[rt][ct] = __builtin_amdgcn_mfma_f32_16x16x32_bf16(aw0, bf[rt][0], acc1[rt][ct], 0, 0, 0);
                acc1[rt][ct] = __builtin_amdgcn_mfma_f32_16x16x32_bf16(aw1, bf[rt][1], acc1[rt][ct], 0, 0, 0);
            }
        }
        #pragma unroll
        for (int ct = 0; ct < 8; ++ct) {
            const f32x4 b1v = *reinterpret_cast<const f32x4*>(g_b1 + ct*16 + lk*4);
            #pragma unroll
            for (int rt = 0; rt < 2; ++rt) {
                const int pt = wid*32 + rt*16 + lr;
                bf16x4 hv;
                #pragma unroll
                for (int r = 0; r < 4; ++r)
                    hv[r] = (__bf16)fmaxf(acc1[rt][ct][r] + b1v[r], 0.0f);
                int a = FB_H1_OFF + pt*256 + ct*32 + lk*8; a ^= (pt & 7) << 4;
                *reinterpret_cast<bf16x4*>(smem + a) = hv;
            }
        }
    }
    __syncthreads();
    const int wr = wid >> 1, wc = wid & 1;
    f32x4 acc2[4][4];
    #pragma unroll
    for (int rt = 0; rt < 4; ++rt)
        #pragma unroll
        for (int ct = 0; ct < 4; ++ct) acc2[rt][ct] = (f32x4){0.f,0.f,0.f,0.f};
    #pragma unroll
    for (int ks = 0; ks < 4; ++ks) {
        bf16x8 a2[4];
        #pragma unroll
        for (int rt = 0; rt < 4; ++rt) {
            const int pt = wr*64 + rt*16 + lr;
            int a = FB_H1_OFF + pt*256 + ks*64 + lk*16; a ^= (pt & 7) << 4;
            a2[rt] = *reinterpret_cast<const bf16x8*>(smem + a);
        }
        #pragma unroll
        for (int ct = 0; ct < 4; ++ct) {
            const int ctg = wc*4 + ct;
            const bf16x8 b2f = wf[1024 + (ctg*4 + ks)*64 + lane];
            #pragma unroll
            for (int rt = 0; rt < 4; ++rt)
                acc2[rt][ct] = __builtin_amdgcn_mfma_f32_16x16x32_bf16(a2[rt], b2f, acc2[rt][ct], 0, 0, 0);
        }
    }
    __syncthreads();
    {
        float b2v[4], w30[4], w31[4], w32[4];
        #pragma unroll
        for (int ct = 0; ct < 4; ++ct) {
            const int n2 = wc*64 + ct*16 + lr;
            b2v[ct] = g_b2[n2];
            w30[ct] = g_w3[n2*3 + 0];
            w31[ct] = g_w3[n2*3 + 1];
            w32[ct] = g_w3[n2*3 + 2];
        }
        #pragma unroll
        for (int rt = 0; rt < 4; ++rt)
            #pragma unroll
            for (int r = 0; r < 4; ++r) {
                float s0 = 0.f, s1 = 0.f, s2 = 0.f;
                #pragma unroll
                for (int ct = 0; ct < 4; ++ct) {
                    const float v = fmaxf(acc2[rt][ct][r] + b2v[ct], 0.0f);
                    s0 = fmaf(v, w30[ct], s0);
                    s1 = fmaf(v, w31[ct], s1);
                    s2 = fmaf(v, w32[ct], s2);
                }
                #pragma unroll
                for (int off = 1; off < 16; off <<= 1) {
                    s0 += __shfl_xor(s0, off);
                    s1 += __shfl_xor(s1, off);
                    s2 += __shfl_xor(s2, off);
                }
                if (lr == 0) {
                    const int pt = wr*64 + rt*16 + lk*4 + r;
                    const int base = FB_PRGB_OFF/4 + (wc*128 + pt)*3;
                    smf[base + 0] = s0;
                    smf[base + 1] = s1;
                    smf[base + 2] = s2;
                }
            }
    }
    __syncthreads();
    if (tid < 128) {
        const int p = tid;
        const float s0 = smf[p*3 + 0] + smf[(128 + p)*3 + 0] + g_b3[0];
        const float s1 = smf[p*3 + 1] + smf[(128 + p)*3 + 1] + g_b3[1];
        const float s2 = smf[p*3 + 2] + smf[(128 + p)*3 + 2] + g_b3[2];
        const int pt = ray*128 + p;
        out_rgb[pt*3 + 0] = 1.0f / (1.0f + expf(-s0));
        out_rgb[pt*3 + 1] = 1.0f / (1.0f + expf(-s1));
        out_rgb[pt*3 + 2] = 1.0f / (1.0f + expf(-s2));
    }
}

extern "C" void kernel_launch(void* const* d_in, const int* in_sizes, int n_in,
                              void* d_out, int out_size, void* d_ws, size_t ws_size,
                              hipStream_t stream)
{
    const float* g_org = (const float*)d_in[0];
    const float* g_dir = (const float*)d_in[1];
    const float* g_len = (const float*)d_in[2];
    const float* g_gd  = (const float*)d_in[3];
    const float* g_gc  = (const float*)d_in[4];
    const float* g_w1  = (const float*)d_in[5];
    const float* g_b1  = (const float*)d_in[6];
    const float* g_w2  = (const float*)d_in[7];
    const float* g_b2  = (const float*)d_in[8];
    const float* g_w3  = (const float*)d_in[9];
    const float* g_b3  = (const float*)d_in[10];
    float* out = (float*)d_out;

    if (ws_size >= NEED_FULL) {
        __bf16* wsb  = (__bf16*)d_ws;
        float*  b1r  = (float*)((char*)d_ws + B1R_B);
        bf16x8* pack = (bf16x8*)((char*)d_ws + PACK2_B);
        __bf16* feat = (__bf16*)((char*)d_ws + FEAT2_B);
        dvgo_prep2<<<6043, 256, 0, stream>>>(g_gd, g_gc, g_w1, g_w2, g_w3, g_dir,
                                             g_b1, pack, wsb, b1r);
        dvgo_gather<<<2048, 256, 0, stream>>>(g_org, g_dir, g_len, pack, feat, out);
        dvgo_mlp<<<4096, 256, 0, stream>>>((const bf16x8*)wsb, b1r, feat,
                                           g_b2, g_b3, out + 4096*128);
    } else if (ws_size >= NEED_PACK) {
        __bf16* wsb  = (__bf16*)d_ws;
        bf16x8* pack = (bf16x8*)((char*)d_ws + EMB_B);
        dvgo_prep_fb<<<4011, 256, 0, stream>>>(g_gd, g_gc, g_w1, g_w2, g_w3, g_dir,
                                               pack, wsb, 3907);
        dvgo_main<true><<<4096, 256, 0, stream>>>(g_org, g_dir, g_len, g_gd, g_gc,
                                                  g_b1, g_b2, g_w3, g_b3,
                                                  (const bf16x8*)wsb, pack,
                                                  out, out + 4096*128);
    } else {
        __bf16* wsb = (__bf16*)d_ws;
        dvgo_prep_fb<<<104, 256, 0, stream>>>(g_gd, g_gc, g_w1, g_w2, g_w3, g_dir,
                                              (bf16x8*)d_ws, wsb, 0);
        dvgo_main<false><<<4096, 256, 0, stream>>>(g_org, g_dir, g_len, g_gd, g_gc,
                                                   g_b1, g_b2, g_w3, g_b3,
                                                   (const bf16x8*)wsb, nullptr,
                                                   out, out + 4096*128);
    }
}

// Round 12
// 83.178 us; speedup vs baseline: 1.4547x; 1.4547x over previous
//
#include <hip/hip_runtime.h>
#include <hip/hip_bf16.h>
#include <math.h>

// DirectVoxGO fused forward, v12.
// prep2: grid pack + weight frags (w1 K=32) + per-ray bias b1r (r9, proven).
// G: gather (256,6) 40-VGPR version (r8, proven; r11's (256,8) spilled -> reverted).
// M v12: ZERO barriers. All three GEMMs pt-sliced: each wave owns 32 pts and a
//   private 8KB LDS slab; GEMM1 (K=32, 8ct x 2q) writes h1 to own slab, GEMM2
//   reads it back (same-wave LDS in-order, v8-proven swizzle pair), GEMM3,
//   sigmoid, coalesced store. Cost vs r9: +6 weight b128/wave; gain: no
//   inter-wave sync -> waves at different phases co-schedule.

typedef __bf16 bf16x4 __attribute__((ext_vector_type(4)));
typedef __bf16 bf16x8 __attribute__((ext_vector_type(8)));
typedef float  f32x4  __attribute__((ext_vector_type(4)));

#define ACT_SHIFT_F (-13.815509557964774f)

// ---- full-path ws layout (bytes) ----
#define B1R_B   45056
#define PACK2_B 2142208
#define FEAT2_B 34142208
#define NEED_FULL 46725120ull

// ---- fallback ws layout (old, unchanged) ----
#define EMB_B   53248
#define PACK_B  315392
#define NEED_PACK 32315392ull

// ================= prep2 (full path) =================
__global__ __launch_bounds__(256)
void dvgo_prep2(const float* __restrict__ g_gd, const float* __restrict__ g_gc,
                const float* __restrict__ g_w1, const float* __restrict__ g_w2,
                const float* __restrict__ g_w3, const float* __restrict__ g_dir,
                const float* __restrict__ g_b1,
                bf16x8* __restrict__ pack, __bf16* __restrict__ wsb,
                float* __restrict__ b1r)
{
    const int bid = blockIdx.x;
    const int tid = threadIdx.x;
    if (bid < 3907) {
        const int gi = bid * 256 + tid;
        if (gi >= 1000000) return;
        bf16x8 v0, v1;
        #pragma unroll
        for (int c = 0; c < 8; ++c) v0[c] = (__bf16)g_gc[c * 1000000 + gi];
        #pragma unroll
        for (int c = 0; c < 4; ++c) v1[c] = (__bf16)g_gc[(8 + c) * 1000000 + gi];
        v1[4] = (__bf16)g_gd[gi];
        v1[5] = (__bf16)0.0f; v1[6] = (__bf16)0.0f; v1[7] = (__bf16)0.0f;
        pack[gi * 2 + 0] = v0;
        pack[gi * 2 + 1] = v1;
        return;
    }
    const int idx2 = bid - 3907;
    if (idx2 < 88) {
        const int idx = idx2 * 256 + tid;
        if (idx < 4096) {                       // w1 A-frags, K=32, k>=12 zero
            const int j = idx & 7, lane = (idx >> 3) & 63, ct = idx >> 9;
            const int n = ct * 16 + (lane & 15);
            const int k = ((lane >> 4) & 3) * 8 + j;
            wsb[idx] = (__bf16)((k < 12) ? g_w1[k * 128 + n] : 0.0f);
        } else if (idx < 20480) {               // w2 A-frags
            const int i2 = idx - 4096;
            const int j = i2 & 7, lane = (i2 >> 3) & 63, ks = (i2 >> 9) & 3, ct = i2 >> 11;
            const int n = ct * 16 + (lane & 15);
            const int k = ks * 32 + ((lane >> 4) & 3) * 8 + j;
            wsb[idx] = (__bf16)g_w2[k * 128 + n];
        } else if (idx < 22528) {               // w3 A-frags, cols >=3 zero
            const int i3 = idx - 20480;
            const int j = i3 & 7, lane = (i3 >> 3) & 63, ks = i3 >> 9;
            const int c = lane & 15;
            const int k = ks * 32 + ((lane >> 4) & 3) * 8 + j;
            wsb[idx] = (__bf16)((c < 3) ? g_w3[k * 3 + c] : 0.0f);
        }
        return;
    }
    // b1r: b1 + emb27 . w1[12:39,:]
    const int rr  = idx2 - 88;
    const int ray = rr * 2 + (tid >> 7);
    const int n   = tid & 127;
    const float d0 = g_dir[ray*3+0], d1 = g_dir[ray*3+1], d2 = g_dir[ray*3+2];
    float s = g_b1[n];
    s += d0 * g_w1[12*128 + n] + d1 * g_w1[13*128 + n] + d2 * g_w1[14*128 + n];
    #pragma unroll
    for (int m = 0; m < 12; ++m) {
        const int i = m >> 2, j = m & 3;
        const float di = (i == 0) ? d0 : ((i == 1) ? d1 : d2);
        const float a = di * (float)(1 << j);
        s += sinf(a) * g_w1[(15 + m)*128 + n];
        s += cosf(a) * g_w1[(27 + m)*128 + n];
    }
    b1r[ray*128 + n] = s;
}

// ================= G: gather, 1 thread/point (r8 proven config) =================
__global__ __launch_bounds__(256, 6)
void dvgo_gather(const float* __restrict__ g_org, const float* __restrict__ g_dir,
                 const float* __restrict__ g_len, const bf16x8* __restrict__ pack,
                 __bf16* __restrict__ feat, float* __restrict__ out_alpha)
{
    const int pt  = blockIdx.x * 256 + threadIdx.x;
    const int ray = pt >> 7;
    const float d0 = g_dir[ray*3+0], d1 = g_dir[ray*3+1], d2 = g_dir[ray*3+2];
    const float o0 = g_org[ray*3+0], o1 = g_org[ray*3+1], o2 = g_org[ray*3+2];
    const float len = g_len[pt];

    const float px = (o0 + d0*len + 1.0f) * 49.5f;
    const float py = (o1 + d1*len + 1.0f) * 49.5f;
    const float pz = (o2 + d2*len + 1.0f) * 49.5f;
    const float fx = floorf(px), fy = floorf(py), fz = floorf(pz);
    const int ix = (int)fx, iy = (int)fy, iz = (int)fz;
    const float qx = px - fx, qy = py - fy, qz = pz - fz;
    const float wxa[2] = {1.0f - qx, qx};
    const float wya[2] = {1.0f - qy, qy};
    const float wza[2] = {1.0f - qz, qz};
    const int  cxa[2] = {min(max(ix,0),99),   min(max(ix+1,0),99)};
    const int  cya[2] = {min(max(iy,0),99),   min(max(iy+1,0),99)};
    const int  cza[2] = {min(max(iz,0),99),   min(max(iz+1,0),99)};
    const bool vxa[2] = {(unsigned)ix < 100u, (unsigned)(ix+1) < 100u};
    const bool vya[2] = {(unsigned)iy < 100u, (unsigned)(iy+1) < 100u};
    const bool vza[2] = {(unsigned)iz < 100u, (unsigned)(iz+1) < 100u};

    float den = 0.0f;
    float cc[12];
    #pragma unroll
    for (int c = 0; c < 12; ++c) cc[c] = 0.0f;

    #pragma unroll
    for (int dz = 0; dz < 2; ++dz)
    #pragma unroll
    for (int dy = 0; dy < 2; ++dy)
    #pragma unroll
    for (int dx = 0; dx < 2; ++dx) {
        float w = wxa[dx] * wya[dy] * wza[dz];
        if (!(vxa[dx] && vya[dy] && vza[dz])) w = 0.0f;
        const int gi = (cza[dz]*100 + cya[dy])*100 + cxa[dx];
        const bf16x8 v0 = pack[gi*2 + 0];
        const bf16x8 v1 = pack[gi*2 + 1];
        #pragma unroll
        for (int c = 0; c < 8; ++c) cc[c]     += w * (float)v0[c];
        #pragma unroll
        for (int c = 0; c < 4; ++c) cc[8 + c] += w * (float)v1[c];
        den += w * (float)v1[4];
    }

    const float interval = sqrtf(d0*d0 + d1*d1 + d2*d2);
    const float e = expf(den + ACT_SHIFT_F);
    out_alpha[pt] = -expm1f(-interval * log1pf(e));

    bf16x8 f0; bf16x4 f1;
    #pragma unroll
    for (int c = 0; c < 8; ++c) f0[c] = (__bf16)cc[c];
    #pragma unroll
    for (int c = 0; c < 4; ++c) f1[c] = (__bf16)cc[8 + c];
    __bf16* fo = feat + (size_t)pt * 12;
    *(bf16x8*)(fo) = f0;
    *(bf16x4*)(fo + 8) = f1;
}

// ================= M: MLP v12 (ZERO barriers, all GEMMs pt-sliced) =================
__global__ __launch_bounds__(256, 4)
void dvgo_mlp(const bf16x8* __restrict__ wf, const float* __restrict__ b1r,
              const __bf16* __restrict__ feat,
              const float* __restrict__ g_b2, const float* __restrict__ g_b3,
              float* __restrict__ out_rgb)
{
    __shared__ __align__(16) char smem[32768];   // 4 wave-private 8KB slabs
    const int tid  = threadIdx.x;
    const int ray  = blockIdx.x;
    const int lane = tid & 63;
    const int wid  = tid >> 6;
    const int lr   = lane & 15;
    const int lk   = lane >> 4;
    const int sz   = (lr & 7) << 4;

    int rb2[4];
    #pragma unroll
    for (int ks = 0; ks < 4; ++ks)
        rb2[ks] = (wid*32 + lr)*256 + ((ks*64 + lk*16) ^ sz);
    const int rowb = (wid*32 + lr)*256;

    bf16x8 zed;
    #pragma unroll
    for (int j = 0; j < 8; ++j) zed[j] = (__bf16)0.0f;

    // ---- feat B-frags for own 2 pt-tiles (K=32: lk0=ch0-7, lk1=ch8-11, rest 0) ----
    bf16x8 bb[2];
    #pragma unroll
    for (int q = 0; q < 2; ++q) {
        const int pt = ray*128 + wid*32 + q*16 + lr;
        const bf16x8 t0 = *(const bf16x8*)(feat + (size_t)pt*12);
        const bf16x4 t1 = *(const bf16x4*)(feat + (size_t)pt*12 + 8);
        bf16x8 tl;
        #pragma unroll
        for (int j = 0; j < 4; ++j) tl[j] = t1[j];
        #pragma unroll
        for (int j = 4; j < 8; ++j) tl[j] = (__bf16)0.0f;
        bb[q] = (lk == 0) ? t0 : ((lk == 1) ? tl : zed);
    }

    // ---- GEMM1 (pt-slice): own 32 pts x all 128 n1; h1 -> own slab ----
    #pragma unroll
    for (int ct = 0; ct < 8; ++ct) {
        const bf16x8 aw = wf[ct*64 + lane];
        f32x4 a0 = (f32x4){0.f,0.f,0.f,0.f};
        f32x4 a1 = (f32x4){0.f,0.f,0.f,0.f};
        a0 = __builtin_amdgcn_mfma_f32_16x16x32_bf16(aw, bb[0], a0, 0, 0, 0);
        a1 = __builtin_amdgcn_mfma_f32_16x16x32_bf16(aw, bb[1], a1, 0, 0, 0);
        const f32x4 b1v = *(const f32x4*)(b1r + ray*128 + ct*16 + lk*4);
        bf16x4 h0, h1;
        #pragma unroll
        for (int r = 0; r < 4; ++r) {
            h0[r] = (__bf16)fmaxf(a0[r] + b1v[r], 0.0f);
            h1[r] = (__bf16)fmaxf(a1[r] + b1v[r], 0.0f);
        }
        const int csw = (ct*32 + lk*8) ^ sz;
        *(bf16x4*)(smem + rowb + csw) = h0;            // h1[own row q=0][n1]
        *(bf16x4*)(smem + rowb + 4096 + csw) = h1;     // h1[own row q=1][n1]
    }

    // ---- GEMM2 (pt-slice): read own h1 (all k) then overwrite slab with h2 ----
    bf16x8 hq[2][4];
    #pragma unroll
    for (int q = 0; q < 2; ++q)
        #pragma unroll
        for (int ks = 0; ks < 4; ++ks)
            hq[q][ks] = *(const bf16x8*)(smem + rb2[ks] + q*4096);

    #pragma unroll
    for (int ct = 0; ct < 8; ++ct) {
        bf16x8 aw2[4];
        #pragma unroll
        for (int ks = 0; ks < 4; ++ks)
            aw2[ks] = wf[512 + (ct*4 + ks)*64 + lane];
        f32x4 a0 = (f32x4){0.f,0.f,0.f,0.f};
        f32x4 a1 = (f32x4){0.f,0.f,0.f,0.f};
        #pragma unroll
        for (int ks = 0; ks < 4; ++ks) {
            a0 = __builtin_amdgcn_mfma_f32_16x16x32_bf16(aw2[ks], hq[0][ks], a0, 0, 0, 0);
            a1 = __builtin_amdgcn_mfma_f32_16x16x32_bf16(aw2[ks], hq[1][ks], a1, 0, 0, 0);
        }
        const f32x4 b2v = *(const f32x4*)(g_b2 + ct*16 + lk*4);
        bf16x4 h0, h1;
        #pragma unroll
        for (int r = 0; r < 4; ++r) {
            h0[r] = (__bf16)fmaxf(a0[r] + b2v[r], 0.0f);
            h1[r] = (__bf16)fmaxf(a1[r] + b2v[r], 0.0f);
        }
        const int csw = (ct*32 + lk*8) ^ sz;
        *(bf16x4*)(smem + rowb + csw) = h0;
        *(bf16x4*)(smem + rowb + 4096 + csw) = h1;
    }

    // ---- GEMM3: own 2 pt-tiles, w3 padded to 16 cols ----
    bf16x8 aw3[4];
    #pragma unroll
    for (int ks = 0; ks < 4; ++ks) aw3[ks] = wf[2560 + ks*64 + lane];
    f32x4 acc3[2];
    acc3[0] = (f32x4){0.f,0.f,0.f,0.f};
    acc3[1] = (f32x4){0.f,0.f,0.f,0.f};
    #pragma unroll
    for (int q = 0; q < 2; ++q)
        #pragma unroll
        for (int ks = 0; ks < 4; ++ks) {
            const bf16x8 hq3 = *(const bf16x8*)(smem + rb2[ks] + q*4096);
            acc3[q] = __builtin_amdgcn_mfma_f32_16x16x32_bf16(aw3[ks], hq3, acc3[q], 0, 0, 0);
        }

    // ---- sigmoid -> wave-private LDS staging -> coalesced store ----
    float* smf = (float*)(smem + wid*8192);
    if (lk == 0) {
        const float b30 = g_b3[0], b31 = g_b3[1], b32 = g_b3[2];
        #pragma unroll
        for (int q = 0; q < 2; ++q) {
            const int o = (q*16 + lr)*3;
            smf[o + 0] = 1.0f / (1.0f + __expf(-(acc3[q][0] + b30)));
            smf[o + 1] = 1.0f / (1.0f + __expf(-(acc3[q][1] + b31)));
            smf[o + 2] = 1.0f / (1.0f + __expf(-(acc3[q][2] + b32)));
        }
    }
    asm volatile("s_waitcnt lgkmcnt(0)");
    __builtin_amdgcn_sched_barrier(0);
    {
        const int base = (ray*128 + wid*32)*3;
        out_rgb[base + lane] = smf[lane];
        if (lane < 32) out_rgb[base + 64 + lane] = smf[64 + lane];
    }
}

// ================= fallback prep (old layout) + fused kernel (v3) =================
__global__ __launch_bounds__(256)
void dvgo_prep_fb(const float* __restrict__ g_gd, const float* __restrict__ g_gc,
                  const float* __restrict__ g_w1, const float* __restrict__ g_w2,
                  const float* __restrict__ g_w3, const float* __restrict__ g_dir,
                  bf16x8* __restrict__ pack, __bf16* __restrict__ wsb, int wbase)
{
    const int bid = blockIdx.x;
    if (bid < wbase) {
        const int gi = bid * 256 + threadIdx.x;
        if (gi >= 1000000) return;
        bf16x8 v0, v1;
        #pragma unroll
        for (int c = 0; c < 8; ++c) v0[c] = (__bf16)g_gc[c * 1000000 + gi];
        #pragma unroll
        for (int c = 0; c < 4; ++c) v1[c] = (__bf16)g_gc[(8 + c) * 1000000 + gi];
        v1[4] = (__bf16)g_gd[gi];
        v1[5] = (__bf16)0.0f; v1[6] = (__bf16)0.0f; v1[7] = (__bf16)0.0f;
        pack[gi * 2 + 0] = v0;
        pack[gi * 2 + 1] = v1;
        return;
    }
    const int idx = (bid - wbase) * 256 + threadIdx.x;
    if (idx < 8192) {
        const int j = idx & 7, lane = (idx >> 3) & 63, ks = (idx >> 9) & 1, ct = idx >> 10;
        const int n = ct * 16 + (lane & 15);
        const int k = ks * 32 + ((lane >> 4) & 3) * 8 + j;
        wsb[idx] = (__bf16)((k < 39) ? g_w1[k * 128 + n] : 0.0f);
    } else if (idx < 24576) {
        const int i2 = idx - 8192;
        const int j = i2 & 7, lane = (i2 >> 3) & 63, ks = (i2 >> 9) & 3, ct = i2 >> 11;
        const int n = ct * 16 + (lane & 15);
        const int k = ks * 32 + ((lane >> 4) & 3) * 8 + j;
        wsb[idx] = (__bf16)g_w2[k * 128 + n];
    }
}

#define FB_FEAT_OFF 0
#define FB_PCC_OFF  16384
#define FB_H1_OFF   0
#define FB_PRGB_OFF 0

template <bool PACKED>
__global__ __launch_bounds__(256, 4)
void dvgo_main(const float* __restrict__ g_org, const float* __restrict__ g_dir,
               const float* __restrict__ g_len, const float* __restrict__ g_gd,
               const float* __restrict__ g_gc, const float* __restrict__ g_b1,
               const float* __restrict__ g_b2, const float* __restrict__ g_w3,
               const float* __restrict__ g_b3, const bf16x8* __restrict__ wf,
               const bf16x8* __restrict__ g_pack,
               float* __restrict__ out_alpha, float* __restrict__ out_rgb)
{
    __shared__ __align__(16) char smem[32768];
    float* smf = (float*)smem;
    const int tid = threadIdx.x;
    const int ray = blockIdx.x;
    const float d0 = g_dir[ray*3+0], d1 = g_dir[ray*3+1], d2 = g_dir[ray*3+2];
    {
        const float o0 = g_org[ray*3+0], o1 = g_org[ray*3+1], o2 = g_org[ray*3+2];
        const int p = tid & 127;
        const int dzv = tid >> 7;
        const float len = g_len[ray*128 + p];
        const float px = (o0 + d0*len + 1.0f) * 49.5f;
        const float py = (o1 + d1*len + 1.0f) * 49.5f;
        const float pz = (o2 + d2*len + 1.0f) * 49.5f;
        const float fx = floorf(px), fy = floorf(py), fz = floorf(pz);
        const int ix = (int)fx, iy = (int)fy, iz0 = (int)fz;
        const float qx = px - fx, qy = py - fy, qz = pz - fz;
        const float wxa[2] = {1.0f - qx, qx};
        const float wya[2] = {1.0f - qy, qy};
        const int  cxa[2] = {min(max(ix,0),99),   min(max(ix+1,0),99)};
        const int  cya[2] = {min(max(iy,0),99),   min(max(iy+1,0),99)};
        const bool vxa[2] = {(unsigned)ix < 100u, (unsigned)(ix+1) < 100u};
        const bool vya[2] = {(unsigned)iy < 100u, (unsigned)(iy+1) < 100u};
        const int  iz = iz0 + dzv;
        const float wz = dzv ? qz : (1.0f - qz);
        const int  cz = min(max(iz,0),99);
        const bool vz = (unsigned)iz < 100u;
        float den = 0.0f;
        float cc[12];
        #pragma unroll
        for (int c = 0; c < 12; ++c) cc[c] = 0.0f;
        #pragma unroll
        for (int dy = 0; dy < 2; ++dy)
        #pragma unroll
        for (int dx = 0; dx < 2; ++dx) {
            float w = wxa[dx] * wya[dy] * wz;
            if (!(vxa[dx] && vya[dy] && vz)) w = 0.0f;
            const int gi = (cz*100 + cya[dy])*100 + cxa[dx];
            if (PACKED) {
                const bf16x8 v0 = g_pack[gi*2 + 0];
                const bf16x8 v1 = g_pack[gi*2 + 1];
                #pragma unroll
                for (int c = 0; c < 8; ++c) cc[c]     += w * (float)v0[c];
                #pragma unroll
                for (int c = 0; c < 4; ++c) cc[8 + c] += w * (float)v1[c];
                den += w * (float)v1[4];
            } else {
                den += w * g_gd[gi];
                #pragma unroll
                for (int c = 0; c < 12; ++c) cc[c] += w * g_gc[c*1000000 + gi];
            }
        }
        if (dzv) {
            #pragma unroll
            for (int c = 0; c < 12; ++c) smf[FB_PCC_OFF/4 + p*13 + c] = cc[c];
            smf[FB_PCC_OFF/4 + p*13 + 12] = den;
        }
        __syncthreads();
        if (!dzv) {
            #pragma unroll
            for (int c = 0; c < 12; ++c) cc[c] += smf[FB_PCC_OFF/4 + p*13 + c];
            den += smf[FB_PCC_OFF/4 + p*13 + 12];
            const float interval = sqrtf(d0*d0 + d1*d1 + d2*d2);
            const float e = expf(den + ACT_SHIFT_F);
            out_alpha[ray*128 + p] = -expm1f(-interval * log1pf(e));
            bf16x8 f0; bf16x4 f1;
            #pragma unroll
            for (int c = 0; c < 8; ++c) f0[c] = (__bf16)cc[c];
            #pragma unroll
            for (int c = 0; c < 4; ++c) f1[c] = (__bf16)cc[8+c];
            const int swz = (p & 7) << 4;
            *reinterpret_cast<bf16x8*>(smem + ((FB_FEAT_OFF + p*128 +  0) ^ swz)) = f0;
            *reinterpret_cast<bf16x4*>(smem + ((FB_FEAT_OFF + p*128 + 16) ^ swz)) = f1;
        } else {
            float vals[52];
            vals[0] = d0; vals[1] = d1; vals[2] = d2;
            #pragma unroll
            for (int i = 0; i < 3; ++i) {
                const float di = (i == 0) ? d0 : ((i == 1) ? d1 : d2);
                #pragma unroll
                for (int j = 0; j < 4; ++j) {
                    const float a = di * (float)(1 << j);
                    vals[3  + i*4 + j] = sinf(a);
                    vals[15 + i*4 + j] = cosf(a);
                }
            }
            #pragma unroll
            for (int c = 27; c < 52; ++c) vals[c] = 0.0f;
            const int swz = (p & 7) << 4;
            #pragma unroll
            for (int i = 0; i < 13; ++i) {
                bf16x4 v4;
                #pragma unroll
                for (int r = 0; r < 4; ++r) v4[r] = (__bf16)vals[i*4 + r];
                *reinterpret_cast<bf16x4*>(smem + ((FB_FEAT_OFF + p*128 + 24 + i*8) ^ swz)) = v4;
            }
        }
    }
    __syncthreads();
    const int lane = tid & 63;
    const int wid  = tid >> 6;
    const int lr   = lane & 15;
    const int lk   = lane >> 4;
    {
        bf16x8 bf[2][2];
        #pragma unroll
        for (int rt = 0; rt < 2; ++rt)
            #pragma unroll
            for (int ks = 0; ks < 2; ++ks) {
                const int pt = wid*32 + rt*16 + lr;
                int a = FB_FEAT_OFF + pt*128 + ks*64 + lk*16; a ^= (pt & 7) << 4;
                bf[rt][ks] = *reinterpret_cast<const bf16x8*>(smem + a);
            }
        __syncthreads();
        f32x4 acc1[2][8];
        #pragma unroll
        for (int rt = 0; rt < 2; ++rt)
            #pragma unroll
            for (int ct = 0; ct < 8; ++ct) acc1[rt][ct] = (f32x4){0.f,0.f,0.f,0.f};
        #pragma unroll
        for (int ct = 0; ct < 8; ++ct) {
            const bf16x8 aw0 = wf[(ct*2 + 0)*64 + lane];
            const bf16x8 aw1 = wf[(ct*2 + 1)*64 + lane];
            #pragma unroll
            for (int rt = 0; rt < 2; ++rt) {
                acc1[rt][ct] = __builtin_amdgcn_mfma_f32_16x16x32_bf16(aw0, bf[rt][0], acc1[rt][ct], 0, 0, 0);
                acc1[rt][ct] = __builtin_amdgcn_mfma_f32_16x16x32_bf16(aw1, bf[rt][1], acc1[rt][ct], 0, 0, 0);
            }
        }
        #pragma unroll
        for (int ct = 0; ct < 8; ++ct) {
            const f32x4 b1v = *reinterpret_cast<const f32x4*>(g_b1 + ct*16 + lk*4);
            #pragma unroll
            for (int rt = 0; rt < 2; ++rt) {
                const int pt = wid*32 + rt*16 + lr;
                bf16x4 hv;
                #pragma unroll
                for (int r = 0; r < 4; ++r)
                    hv[r] = (__bf16)fmaxf(acc1[rt][ct][r] + b1v[r], 0.0f);
                int a = FB_H1_OFF + pt*256 + ct*32 + lk*8; a ^= (pt & 7) << 4;
                *reinterpret_cast<bf16x4*>(smem + a) = hv;
            }
        }
    }
    __syncthreads();
    const int wr = wid >> 1, wc = wid & 1;
    f32x4 acc2[4][4];
    #pragma unroll
    for (int rt = 0; rt < 4; ++rt)
        #pragma unroll
        for (int ct = 0; ct < 4; ++ct) acc2[rt][ct] = (f32x4){0.f,0.f,0.f,0.f};
    #pragma unroll
    for (int ks = 0; ks < 4; ++ks) {
        bf16x8 a2[4];
        #pragma unroll
        for (int rt = 0; rt < 4; ++rt) {
            const int pt = wr*64 + rt*16 + lr;
            int a = FB_H1_OFF + pt*256 + ks*64 + lk*16; a ^= (pt & 7) << 4;
            a2[rt] = *reinterpret_cast<const bf16x8*>(smem + a);
        }
        #pragma unroll
        for (int ct = 0; ct < 4; ++ct) {
            const int ctg = wc*4 + ct;
            const bf16x8 b2f = wf[1024 + (ctg*4 + ks)*64 + lane];
            #pragma unroll
            for (int rt = 0; rt < 4; ++rt)
                acc2[rt][ct] = __builtin_amdgcn_mfma_f32_16x16x32_bf16(a2[rt], b2f, acc2[rt][ct], 0, 0, 0);
        }
    }
    __syncthreads();
    {
        float b2v[4], w30[4], w31[4], w32[4];
        #pragma unroll
        for (int ct = 0; ct < 4; ++ct) {
            const int n2 = wc*64 + ct*16 + lr;
            b2v[ct] = g_b2[n2];
            w30[ct] = g_w3[n2*3 + 0];
            w31[ct] = g_w3[n2*3 + 1];
            w32[ct] = g_w3[n2*3 + 2];
        }
        #pragma unroll
        for (int rt = 0; rt < 4; ++rt)
            #pragma unroll
            for (int r = 0; r < 4; ++r) {
                float s0 = 0.f, s1 = 0.f, s2 = 0.f;
                #pragma unroll
                for (int ct = 0; ct < 4; ++ct) {
                    const float v = fmaxf(acc2[rt][ct][r] + b2v[ct], 0.0f);
                    s0 = fmaf(v, w30[ct], s0);
                    s1 = fmaf(v, w31[ct], s1);
                    s2 = fmaf(v, w32[ct], s2);
                }
                #pragma unroll
                for (int off = 1; off < 16; off <<= 1) {
                    s0 += __shfl_xor(s0, off);
                    s1 += __shfl_xor(s1, off);
                    s2 += __shfl_xor(s2, off);
                }
                if (lr == 0) {
                    const int pt = wr*64 + rt*16 + lk*4 + r;
                    const int base = FB_PRGB_OFF/4 + (wc*128 + pt)*3;
                    smf[base + 0] = s0;
                    smf[base + 1] = s1;
                    smf[base + 2] = s2;
                }
            }
    }
    __syncthreads();
    if (tid < 128) {
        const int p = tid;
        const float s0 = smf[p*3 + 0] + smf[(128 + p)*3 + 0] + g_b3[0];
        const float s1 = smf[p*3 + 1] + smf[(128 + p)*3 + 1] + g_b3[1];
        const float s2 = smf[p*3 + 2] + smf[(128 + p)*3 + 2] + g_b3[2];
        const int pt = ray*128 + p;
        out_rgb[pt*3 + 0] = 1.0f / (1.0f + expf(-s0));
        out_rgb[pt*3 + 1] = 1.0f / (1.0f + expf(-s1));
        out_rgb[pt*3 + 2] = 1.0f / (1.0f + expf(-s2));
    }
}

extern "C" void kernel_launch(void* const* d_in, const int* in_sizes, int n_in,
                              void* d_out, int out_size, void* d_ws, size_t ws_size,
                              hipStream_t stream)
{
    const float* g_org = (const float*)d_in[0];
    const float* g_dir = (const float*)d_in[1];
    const float* g_len = (const float*)d_in[2];
    const float* g_gd  = (const float*)d_in[3];
    const float* g_gc  = (const float*)d_in[4];
    const float* g_w1  = (const float*)d_in[5];
    const float* g_b1  = (const float*)d_in[6];
    const float* g_w2  = (const float*)d_in[7];
    const float* g_b2  = (const float*)d_in[8];
    const float* g_w3  = (const float*)d_in[9];
    const float* g_b3  = (const float*)d_in[10];
    float* out = (float*)d_out;

    if (ws_size >= NEED_FULL) {
        __bf16* wsb  = (__bf16*)d_ws;
        float*  b1r  = (float*)((char*)d_ws + B1R_B);
        bf16x8* pack = (bf16x8*)((char*)d_ws + PACK2_B);
        __bf16* feat = (__bf16*)((char*)d_ws + FEAT2_B);
        dvgo_prep2<<<6043, 256, 0, stream>>>(g_gd, g_gc, g_w1, g_w2, g_w3, g_dir,
                                             g_b1, pack, wsb, b1r);
        dvgo_gather<<<2048, 256, 0, stream>>>(g_org, g_dir, g_len, pack, feat, out);
        dvgo_mlp<<<4096, 256, 0, stream>>>((const bf16x8*)wsb, b1r, feat,
                                           g_b2, g_b3, out + 4096*128);
    } else if (ws_size >= NEED_PACK) {
        __bf16* wsb  = (__bf16*)d_ws;
        bf16x8* pack = (bf16x8*)((char*)d_ws + EMB_B);
        dvgo_prep_fb<<<4011, 256, 0, stream>>>(g_gd, g_gc, g_w1, g_w2, g_w3, g_dir,
                                               pack, wsb, 3907);
        dvgo_main<true><<<4096, 256, 0, stream>>>(g_org, g_dir, g_len, g_gd, g_gc,
                                                  g_b1, g_b2, g_w3, g_b3,
                                                  (const bf16x8*)wsb, pack,
                                                  out, out + 4096*128);
    } else {
        __bf16* wsb = (__bf16*)d_ws;
        dvgo_prep_fb<<<104, 256, 0, stream>>>(g_gd, g_gc, g_w1, g_w2, g_w3, g_dir,
                                              (bf16x8*)d_ws, wsb, 0);
        dvgo_main<false><<<4096, 256, 0, stream>>>(g_org, g_dir, g_len, g_gd, g_gc,
                                                   g_b1, g_b2, g_w3, g_b3,
                                                   (const bf16x8*)wsb, nullptr,
                                                   out, out + 4096*128);
    }
}

// Round 13
// 73.259 us; speedup vs baseline: 1.6517x; 1.1354x over previous
//
#include <hip/hip_runtime.h>
#include <hip/hip_bf16.h>
#include <math.h>

// DirectVoxGO fused forward, v13.
// prep2: grid pack + weight frags (w1 K=32) + per-ray f32 bias b1r (r9 proven).
// M v13: gather FUSED into the zero-barrier MLP (v12). Per wave (32 own pts):
//   2 lanes/pt dz-split gather (8 b128 pack loads/lane, issued together) ->
//   shfl_xor(32) combine -> alpha store + feat staged via own LDS slab (1KB,
//   consumed into B-frags before h1 overwrites) -> v12 GEMM1/2/3 -> rgb.
//   aw1 weight prefetch issued at entry hides under gather latency. No feat
//   round-trip, one fewer kernel launch, phase-diverse wave co-scheduling.

typedef __bf16 bf16x4 __attribute__((ext_vector_type(4)));
typedef __bf16 bf16x8 __attribute__((ext_vector_type(8)));
typedef float  f32x4  __attribute__((ext_vector_type(4)));

#define ACT_SHIFT_F (-13.815509557964774f)

// ---- full-path ws layout (bytes) ----
#define B1R_B   45056
#define PACK2_B 2142208
#define NEED_FULL 34142208ull     // pack end (feat region no longer used)

// ---- fallback ws layout (old, unchanged) ----
#define EMB_B   53248
#define PACK_B  315392
#define NEED_PACK 32315392ull

// ================= prep2 (full path) =================
__global__ __launch_bounds__(256)
void dvgo_prep2(const float* __restrict__ g_gd, const float* __restrict__ g_gc,
                const float* __restrict__ g_w1, const float* __restrict__ g_w2,
                const float* __restrict__ g_w3, const float* __restrict__ g_dir,
                const float* __restrict__ g_b1,
                bf16x8* __restrict__ pack, __bf16* __restrict__ wsb,
                float* __restrict__ b1r)
{
    const int bid = blockIdx.x;
    const int tid = threadIdx.x;
    if (bid < 3907) {
        const int gi = bid * 256 + tid;
        if (gi >= 1000000) return;
        bf16x8 v0, v1;
        #pragma unroll
        for (int c = 0; c < 8; ++c) v0[c] = (__bf16)g_gc[c * 1000000 + gi];
        #pragma unroll
        for (int c = 0; c < 4; ++c) v1[c] = (__bf16)g_gc[(8 + c) * 1000000 + gi];
        v1[4] = (__bf16)g_gd[gi];
        v1[5] = (__bf16)0.0f; v1[6] = (__bf16)0.0f; v1[7] = (__bf16)0.0f;
        pack[gi * 2 + 0] = v0;
        pack[gi * 2 + 1] = v1;
        return;
    }
    const int idx2 = bid - 3907;
    if (idx2 < 88) {
        const int idx = idx2 * 256 + tid;
        if (idx < 4096) {                       // w1 A-frags, K=32, k>=12 zero
            const int j = idx & 7, lane = (idx >> 3) & 63, ct = idx >> 9;
            const int n = ct * 16 + (lane & 15);
            const int k = ((lane >> 4) & 3) * 8 + j;
            wsb[idx] = (__bf16)((k < 12) ? g_w1[k * 128 + n] : 0.0f);
        } else if (idx < 20480) {               // w2 A-frags
            const int i2 = idx - 4096;
            const int j = i2 & 7, lane = (i2 >> 3) & 63, ks = (i2 >> 9) & 3, ct = i2 >> 11;
            const int n = ct * 16 + (lane & 15);
            const int k = ks * 32 + ((lane >> 4) & 3) * 8 + j;
            wsb[idx] = (__bf16)g_w2[k * 128 + n];
        } else if (idx < 22528) {               // w3 A-frags, cols >=3 zero
            const int i3 = idx - 20480;
            const int j = i3 & 7, lane = (i3 >> 3) & 63, ks = i3 >> 9;
            const int c = lane & 15;
            const int k = ks * 32 + ((lane >> 4) & 3) * 8 + j;
            wsb[idx] = (__bf16)((c < 3) ? g_w3[k * 3 + c] : 0.0f);
        }
        return;
    }
    // b1r: b1 + emb27 . w1[12:39,:]
    const int rr  = idx2 - 88;
    const int ray = rr * 2 + (tid >> 7);
    const int n   = tid & 127;
    const float d0 = g_dir[ray*3+0], d1 = g_dir[ray*3+1], d2 = g_dir[ray*3+2];
    float s = g_b1[n];
    s += d0 * g_w1[12*128 + n] + d1 * g_w1[13*128 + n] + d2 * g_w1[14*128 + n];
    #pragma unroll
    for (int m = 0; m < 12; ++m) {
        const int i = m >> 2, j = m & 3;
        const float di = (i == 0) ? d0 : ((i == 1) ? d1 : d2);
        const float a = di * (float)(1 << j);
        s += sinf(a) * g_w1[(15 + m)*128 + n];
        s += cosf(a) * g_w1[(27 + m)*128 + n];
    }
    b1r[ray*128 + n] = s;
}

// ================= M: fused gather + MLP (zero barriers) =================
__global__ __launch_bounds__(256, 4)
void dvgo_mlp(const bf16x8* __restrict__ wf, const float* __restrict__ b1r,
              const bf16x8* __restrict__ pack,
              const float* __restrict__ g_org, const float* __restrict__ g_dir,
              const float* __restrict__ g_len,
              const float* __restrict__ g_b2, const float* __restrict__ g_b3,
              float* __restrict__ out_alpha, float* __restrict__ out_rgb)
{
    __shared__ __align__(16) char smem[32768];   // 4 wave-private 8KB slabs
    const int tid  = threadIdx.x;
    const int ray  = blockIdx.x;
    const int lane = tid & 63;
    const int wid  = tid >> 6;
    const int lr   = lane & 15;
    const int lk   = lane >> 4;
    const int sz   = (lr & 7) << 4;
    char* slab = smem + wid*8192;

    // ---- prefetch GEMM1 weights at entry (land during gather) ----
    bf16x8 aw1[8];
    #pragma unroll
    for (int ct = 0; ct < 8; ++ct) aw1[ct] = wf[ct*64 + lane];

    // ================= gather phase: 2 lanes/pt, dz split =================
    {
        const int p    = wid*32 + (lane & 31);    // own point within ray
        const int dzv  = lane >> 5;
        const float d0 = g_dir[ray*3+0], d1 = g_dir[ray*3+1], d2 = g_dir[ray*3+2];
        const float o0 = g_org[ray*3+0], o1 = g_org[ray*3+1], o2 = g_org[ray*3+2];
        const float len = g_len[ray*128 + p];

        const float px = (o0 + d0*len + 1.0f) * 49.5f;
        const float py = (o1 + d1*len + 1.0f) * 49.5f;
        const float pz = (o2 + d2*len + 1.0f) * 49.5f;
        const float fx = floorf(px), fy = floorf(py), fz = floorf(pz);
        const int ix = (int)fx, iy = (int)fy, iz0 = (int)fz;
        const float qx = px - fx, qy = py - fy, qz = pz - fz;
        const float wxa[2] = {1.0f - qx, qx};
        const float wya[2] = {1.0f - qy, qy};
        const int  cxa[2] = {min(max(ix,0),99),   min(max(ix+1,0),99)};
        const int  cya[2] = {min(max(iy,0),99),   min(max(iy+1,0),99)};
        const bool vxa[2] = {(unsigned)ix < 100u, (unsigned)(ix+1) < 100u};
        const bool vya[2] = {(unsigned)iy < 100u, (unsigned)(iy+1) < 100u};
        const int  iz = iz0 + dzv;
        const float wz = dzv ? qz : (1.0f - qz);
        const int  cz = min(max(iz,0),99);
        const bool vz = (unsigned)iz < 100u;

        float den = 0.0f;
        float cc[12];
        #pragma unroll
        for (int c = 0; c < 12; ++c) cc[c] = 0.0f;

        #pragma unroll
        for (int dy = 0; dy < 2; ++dy)
        #pragma unroll
        for (int dx = 0; dx < 2; ++dx) {
            float w = wxa[dx] * wya[dy] * wz;
            if (!(vxa[dx] && vya[dy] && vz)) w = 0.0f;
            const int gi = (cz*100 + cya[dy])*100 + cxa[dx];
            const bf16x8 v0 = pack[gi*2 + 0];
            const bf16x8 v1 = pack[gi*2 + 1];
            #pragma unroll
            for (int c = 0; c < 8; ++c) cc[c]     += w * (float)v0[c];
            #pragma unroll
            for (int c = 0; c < 4; ++c) cc[8 + c] += w * (float)v1[c];
            den += w * (float)v1[4];
        }

        // combine dz halves (lane ^ 32)
        #pragma unroll
        for (int c = 0; c < 12; ++c) cc[c] += __shfl_xor(cc[c], 32);
        den += __shfl_xor(den, 32);

        if (dzv == 0) {
            const float interval = sqrtf(d0*d0 + d1*d1 + d2*d2);
            const float e = expf(den + ACT_SHIFT_F);
            out_alpha[ray*128 + p] = -expm1f(-interval * log1pf(e));
            // stage feat -> own slab [pt&31][32B]: ch0-7 | ch8-11 + zero pad
            bf16x8 f0, f1;
            #pragma unroll
            for (int c = 0; c < 8; ++c) f0[c] = (__bf16)cc[c];
            #pragma unroll
            for (int c = 0; c < 4; ++c) f1[c] = (__bf16)cc[8 + c];
            #pragma unroll
            for (int c = 4; c < 8; ++c) f1[c] = (__bf16)0.0f;
            *(bf16x8*)(slab + (lane & 31)*32 +  0) = f0;
            *(bf16x8*)(slab + (lane & 31)*32 + 16) = f1;
        }
    }

    // ---- feat B-frags from own slab (consumed before h1 overwrites) ----
    bf16x8 zed;
    #pragma unroll
    for (int j = 0; j < 8; ++j) zed[j] = (__bf16)0.0f;
    bf16x8 bb[2];
    #pragma unroll
    for (int q = 0; q < 2; ++q) {
        const bf16x8 t = *(const bf16x8*)(slab + (q*16 + lr)*32 + (lk & 1)*16);
        bb[q] = (lk < 2) ? t : zed;
    }

    const int rowb = (wid*32 + lr)*256;
    int rb2[4];
    #pragma unroll
    for (int ks = 0; ks < 4; ++ks)
        rb2[ks] = rowb + ((ks*64 + lk*16) ^ sz);

    // ---- GEMM1 (pt-slice): own 32 pts x all 128 n1; h1 -> own slab ----
    #pragma unroll
    for (int ct = 0; ct < 8; ++ct) {
        f32x4 a0 = (f32x4){0.f,0.f,0.f,0.f};
        f32x4 a1 = (f32x4){0.f,0.f,0.f,0.f};
        a0 = __builtin_amdgcn_mfma_f32_16x16x32_bf16(aw1[ct], bb[0], a0, 0, 0, 0);
        a1 = __builtin_amdgcn_mfma_f32_16x16x32_bf16(aw1[ct], bb[1], a1, 0, 0, 0);
        const f32x4 b1v = *(const f32x4*)(b1r + ray*128 + ct*16 + lk*4);
        bf16x4 h0, h1;
        #pragma unroll
        for (int r = 0; r < 4; ++r) {
            h0[r] = (__bf16)fmaxf(a0[r] + b1v[r], 0.0f);
            h1[r] = (__bf16)fmaxf(a1[r] + b1v[r], 0.0f);
        }
        const int csw = (ct*32 + lk*8) ^ sz;
        *(bf16x4*)(smem + rowb + csw) = h0;
        *(bf16x4*)(smem + rowb + 4096 + csw) = h1;
    }

    // ---- GEMM2 (pt-slice): read own h1 (all k) then overwrite slab with h2 ----
    bf16x8 hq[2][4];
    #pragma unroll
    for (int q = 0; q < 2; ++q)
        #pragma unroll
        for (int ks = 0; ks < 4; ++ks)
            hq[q][ks] = *(const bf16x8*)(smem + rb2[ks] + q*4096);

    #pragma unroll
    for (int ct = 0; ct < 8; ++ct) {
        bf16x8 aw2[4];
        #pragma unroll
        for (int ks = 0; ks < 4; ++ks)
            aw2[ks] = wf[512 + (ct*4 + ks)*64 + lane];
        f32x4 a0 = (f32x4){0.f,0.f,0.f,0.f};
        f32x4 a1 = (f32x4){0.f,0.f,0.f,0.f};
        #pragma unroll
        for (int ks = 0; ks < 4; ++ks) {
            a0 = __builtin_amdgcn_mfma_f32_16x16x32_bf16(aw2[ks], hq[0][ks], a0, 0, 0, 0);
            a1 = __builtin_amdgcn_mfma_f32_16x16x32_bf16(aw2[ks], hq[1][ks], a1, 0, 0, 0);
        }
        const f32x4 b2v = *(const f32x4*)(g_b2 + ct*16 + lk*4);
        bf16x4 h0, h1;
        #pragma unroll
        for (int r = 0; r < 4; ++r) {
            h0[r] = (__bf16)fmaxf(a0[r] + b2v[r], 0.0f);
            h1[r] = (__bf16)fmaxf(a1[r] + b2v[r], 0.0f);
        }
        const int csw = (ct*32 + lk*8) ^ sz;
        *(bf16x4*)(smem + rowb + csw) = h0;
        *(bf16x4*)(smem + rowb + 4096 + csw) = h1;
    }

    // ---- GEMM3: own 2 pt-tiles, w3 padded to 16 cols ----
    bf16x8 aw3[4];
    #pragma unroll
    for (int ks = 0; ks < 4; ++ks) aw3[ks] = wf[2560 + ks*64 + lane];
    f32x4 acc3[2];
    acc3[0] = (f32x4){0.f,0.f,0.f,0.f};
    acc3[1] = (f32x4){0.f,0.f,0.f,0.f};
    #pragma unroll
    for (int q = 0; q < 2; ++q)
        #pragma unroll
        for (int ks = 0; ks < 4; ++ks) {
            const bf16x8 hq3 = *(const bf16x8*)(smem + rb2[ks] + q*4096);
            acc3[q] = __builtin_amdgcn_mfma_f32_16x16x32_bf16(aw3[ks], hq3, acc3[q], 0, 0, 0);
        }

    // ---- sigmoid -> wave-private LDS staging -> coalesced store ----
    float* smf = (float*)slab;
    if (lk == 0) {
        const float b30 = g_b3[0], b31 = g_b3[1], b32 = g_b3[2];
        #pragma unroll
        for (int q = 0; q < 2; ++q) {
            const int o = (q*16 + lr)*3;
            smf[o + 0] = 1.0f / (1.0f + __expf(-(acc3[q][0] + b30)));
            smf[o + 1] = 1.0f / (1.0f + __expf(-(acc3[q][1] + b31)));
            smf[o + 2] = 1.0f / (1.0f + __expf(-(acc3[q][2] + b32)));
        }
    }
    asm volatile("s_waitcnt lgkmcnt(0)");
    __builtin_amdgcn_sched_barrier(0);
    {
        const int base = (ray*128 + wid*32)*3;
        out_rgb[base + lane] = smf[lane];
        if (lane < 32) out_rgb[base + 64 + lane] = smf[64 + lane];
    }
}

// ================= fallback prep (old layout) + fused kernel (v3) =================
__global__ __launch_bounds__(256)
void dvgo_prep_fb(const float* __restrict__ g_gd, const float* __restrict__ g_gc,
                  const float* __restrict__ g_w1, const float* __restrict__ g_w2,
                  const float* __restrict__ g_w3, const float* __restrict__ g_dir,
                  bf16x8* __restrict__ pack, __bf16* __restrict__ wsb, int wbase)
{
    const int bid = blockIdx.x;
    if (bid < wbase) {
        const int gi = bid * 256 + threadIdx.x;
        if (gi >= 1000000) return;
        bf16x8 v0, v1;
        #pragma unroll
        for (int c = 0; c < 8; ++c) v0[c] = (__bf16)g_gc[c * 1000000 + gi];
        #pragma unroll
        for (int c = 0; c < 4; ++c) v1[c] = (__bf16)g_gc[(8 + c) * 1000000 + gi];
        v1[4] = (__bf16)g_gd[gi];
        v1[5] = (__bf16)0.0f; v1[6] = (__bf16)0.0f; v1[7] = (__bf16)0.0f;
        pack[gi * 2 + 0] = v0;
        pack[gi * 2 + 1] = v1;
        return;
    }
    const int idx = (bid - wbase) * 256 + threadIdx.x;
    if (idx < 8192) {
        const int j = idx & 7, lane = (idx >> 3) & 63, ks = (idx >> 9) & 1, ct = idx >> 10;
        const int n = ct * 16 + (lane & 15);
        const int k = ks * 32 + ((lane >> 4) & 3) * 8 + j;
        wsb[idx] = (__bf16)((k < 39) ? g_w1[k * 128 + n] : 0.0f);
    } else if (idx < 24576) {
        const int i2 = idx - 8192;
        const int j = i2 & 7, lane = (i2 >> 3) & 63, ks = (i2 >> 9) & 3, ct = i2 >> 11;
        const int n = ct * 16 + (lane & 15);
        const int k = ks * 32 + ((lane >> 4) & 3) * 8 + j;
        wsb[idx] = (__bf16)g_w2[k * 128 + n];
    }
}

#define FB_FEAT_OFF 0
#define FB_PCC_OFF  16384
#define FB_H1_OFF   0
#define FB_PRGB_OFF 0

template <bool PACKED>
__global__ __launch_bounds__(256, 4)
void dvgo_main(const float* __restrict__ g_org, const float* __restrict__ g_dir,
               const float* __restrict__ g_len, const float* __restrict__ g_gd,
               const float* __restrict__ g_gc, const float* __restrict__ g_b1,
               const float* __restrict__ g_b2, const float* __restrict__ g_w3,
               const float* __restrict__ g_b3, const bf16x8* __restrict__ wf,
               const bf16x8* __restrict__ g_pack,
               float* __restrict__ out_alpha, float* __restrict__ out_rgb)
{
    __shared__ __align__(16) char smem[32768];
    float* smf = (float*)smem;
    const int tid = threadIdx.x;
    const int ray = blockIdx.x;
    const float d0 = g_dir[ray*3+0], d1 = g_dir[ray*3+1], d2 = g_dir[ray*3+2];
    {
        const float o0 = g_org[ray*3+0], o1 = g_org[ray*3+1], o2 = g_org[ray*3+2];
        const int p = tid & 127;
        const int dzv = tid >> 7;
        const float len = g_len[ray*128 + p];
        const float px = (o0 + d0*len + 1.0f) * 49.5f;
        const float py = (o1 + d1*len + 1.0f) * 49.5f;
        const float pz = (o2 + d2*len + 1.0f) * 49.5f;
        const float fx = floorf(px), fy = floorf(py), fz = floorf(pz);
        const int ix = (int)fx, iy = (int)fy, iz0 = (int)fz;
        const float qx = px - fx, qy = py - fy, qz = pz - fz;
        const float wxa[2] = {1.0f - qx, qx};
        const float wya[2] = {1.0f - qy, qy};
        const int  cxa[2] = {min(max(ix,0),99),   min(max(ix+1,0),99)};
        const int  cya[2] = {min(max(iy,0),99),   min(max(iy+1,0),99)};
        const bool vxa[2] = {(unsigned)ix < 100u, (unsigned)(ix+1) < 100u};
        const bool vya[2] = {(unsigned)iy < 100u, (unsigned)(iy+1) < 100u};
        const int  iz = iz0 + dzv;
        const float wz = dzv ? qz : (1.0f - qz);
        const int  cz = min(max(iz,0),99);
        const bool vz = (unsigned)iz < 100u;
        float den = 0.0f;
        float cc[12];
        #pragma unroll
        for (int c = 0; c < 12; ++c) cc[c] = 0.0f;
        #pragma unroll
        for (int dy = 0; dy < 2; ++dy)
        #pragma unroll
        for (int dx = 0; dx < 2; ++dx) {
            float w = wxa[dx] * wya[dy] * wz;
            if (!(vxa[dx] && vya[dy] && vz)) w = 0.0f;
            const int gi = (cz*100 + cya[dy])*100 + cxa[dx];
            if (PACKED) {
                const bf16x8 v0 = g_pack[gi*2 + 0];
                const bf16x8 v1 = g_pack[gi*2 + 1];
                #pragma unroll
                for (int c = 0; c < 8; ++c) cc[c]     += w * (float)v0[c];
                #pragma unroll
                for (int c = 0; c < 4; ++c) cc[8 + c] += w * (float)v1[c];
                den += w * (float)v1[4];
            } else {
                den += w * g_gd[gi];
                #pragma unroll
                for (int c = 0; c < 12; ++c) cc[c] += w * g_gc[c*1000000 + gi];
            }
        }
        if (dzv) {
            #pragma unroll
            for (int c = 0; c < 12; ++c) smf[FB_PCC_OFF/4 + p*13 + c] = cc[c];
            smf[FB_PCC_OFF/4 + p*13 + 12] = den;
        }
        __syncthreads();
        if (!dzv) {
            #pragma unroll
            for (int c = 0; c < 12; ++c) cc[c] += smf[FB_PCC_OFF/4 + p*13 + c];
            den += smf[FB_PCC_OFF/4 + p*13 + 12];
            const float interval = sqrtf(d0*d0 + d1*d1 + d2*d2);
            const float e = expf(den + ACT_SHIFT_F);
            out_alpha[ray*128 + p] = -expm1f(-interval * log1pf(e));
            bf16x8 f0; bf16x4 f1;
            #pragma unroll
            for (int c = 0; c < 8; ++c) f0[c] = (__bf16)cc[c];
            #pragma unroll
            for (int c = 0; c < 4; ++c) f1[c] = (__bf16)cc[8+c];
            const int swz = (p & 7) << 4;
            *reinterpret_cast<bf16x8*>(smem + ((FB_FEAT_OFF + p*128 +  0) ^ swz)) = f0;
            *reinterpret_cast<bf16x4*>(smem + ((FB_FEAT_OFF + p*128 + 16) ^ swz)) = f1;
        } else {
            float vals[52];
            vals[0] = d0; vals[1] = d1; vals[2] = d2;
            #pragma unroll
            for (int i = 0; i < 3; ++i) {
                const float di = (i == 0) ? d0 : ((i == 1) ? d1 : d2);
                #pragma unroll
                for (int j = 0; j < 4; ++j) {
                    const float a = di * (float)(1 << j);
                    vals[3  + i*4 + j] = sinf(a);
                    vals[15 + i*4 + j] = cosf(a);
                }
            }
            #pragma unroll
            for (int c = 27; c < 52; ++c) vals[c] = 0.0f;
            const int swz = (p & 7) << 4;
            #pragma unroll
            for (int i = 0; i < 13; ++i) {
                bf16x4 v4;
                #pragma unroll
                for (int r = 0; r < 4; ++r) v4[r] = (__bf16)vals[i*4 + r];
                *reinterpret_cast<bf16x4*>(smem + ((FB_FEAT_OFF + p*128 + 24 + i*8) ^ swz)) = v4;
            }
        }
    }
    __syncthreads();
    const int lane = tid & 63;
    const int wid  = tid >> 6;
    const int lr   = lane & 15;
    const int lk   = lane >> 4;
    {
        bf16x8 bf[2][2];
        #pragma unroll
        for (int rt = 0; rt < 2; ++rt)
            #pragma unroll
            for (int ks = 0; ks < 2; ++ks) {
                const int pt = wid*32 + rt*16 + lr;
                int a = FB_FEAT_OFF + pt*128 + ks*64 + lk*16; a ^= (pt & 7) << 4;
                bf[rt][ks] = *reinterpret_cast<const bf16x8*>(smem + a);
            }
        __syncthreads();
        f32x4 acc1[2][8];
        #pragma unroll
        for (int rt = 0; rt < 2; ++rt)
            #pragma unroll
            for (int ct = 0; ct < 8; ++ct) acc1[rt][ct] = (f32x4){0.f,0.f,0.f,0.f};
        #pragma unroll
        for (int ct = 0; ct < 8; ++ct) {
            const bf16x8 aw0 = wf[(ct*2 + 0)*64 + lane];
            const bf16x8 aw1 = wf[(ct*2 + 1)*64 + lane];
            #pragma unroll
            for (int rt = 0; rt < 2; ++rt) {
                acc1[rt][ct] = __builtin_amdgcn_mfma_f32_16x16x32_bf16(aw0, bf[rt][0], acc1[rt][ct], 0, 0, 0);
                acc1[rt][ct] = __builtin_amdgcn_mfma_f32_16x16x32_bf16(aw1, bf[rt][1], acc1[rt][ct], 0, 0, 0);
            }
        }
        #pragma unroll
        for (int ct = 0; ct < 8; ++ct) {
            const f32x4 b1v = *reinterpret_cast<const f32x4*>(g_b1 + ct*16 + lk*4);
            #pragma unroll
            for (int rt = 0; rt < 2; ++rt) {
                const int pt = wid*32 + rt*16 + lr;
                bf16x4 hv;
                #pragma unroll
                for (int r = 0; r < 4; ++r)
                    hv[r] = (__bf16)fmaxf(acc1[rt][ct][r] + b1v[r], 0.0f);
                int a = FB_H1_OFF + pt*256 + ct*32 + lk*8; a ^= (pt & 7) << 4;
                *reinterpret_cast<bf16x4*>(smem + a) = hv;
            }
        }
    }
    __syncthreads();
    const int wr = wid >> 1, wc = wid & 1;
    f32x4 acc2[4][4];
    #pragma unroll
    for (int rt = 0; rt < 4; ++rt)
        #pragma unroll
        for (int ct = 0; ct < 4; ++ct) acc2[rt][ct] = (f32x4){0.f,0.f,0.f,0.f};
    #pragma unroll
    for (int ks = 0; ks < 4; ++ks) {
        bf16x8 a2[4];
        #pragma unroll
        for (int rt = 0; rt < 4; ++rt) {
            const int pt = wr*64 + rt*16 + lr;
            int a = FB_H1_OFF + pt*256 + ks*64 + lk*16; a ^= (pt & 7) << 4;
            a2[rt] = *reinterpret_cast<const bf16x8*>(smem + a);
        }
        #pragma unroll
        for (int ct = 0; ct < 4; ++ct) {
            const int ctg = wc*4 + ct;
            const bf16x8 b2f = wf[1024 + (ctg*4 + ks)*64 + lane];
            #pragma unroll
            for (int rt = 0; rt < 4; ++rt)
                acc2[rt][ct] = __builtin_amdgcn_mfma_f32_16x16x32_bf16(a2[rt], b2f, acc2[rt][ct], 0, 0, 0);
        }
    }
    __syncthreads();
    {
        float b2v[4], w30[4], w31[4], w32[4];
        #pragma unroll
        for (int ct = 0; ct < 4; ++ct) {
            const int n2 = wc*64 + ct*16 + lr;
            b2v[ct] = g_b2[n2];
            w30[ct] = g_w3[n2*3 + 0];
            w31[ct] = g_w3[n2*3 + 1];
            w32[ct] = g_w3[n2*3 + 2];
        }
        #pragma unroll
        for (int rt = 0; rt < 4; ++rt)
            #pragma unroll
            for (int r = 0; r < 4; ++r) {
                float s0 = 0.f, s1 = 0.f, s2 = 0.f;
                #pragma unroll
                for (int ct = 0; ct < 4; ++ct) {
                    const float v = fmaxf(acc2[rt][ct][r] + b2v[ct], 0.0f);
                    s0 = fmaf(v, w30[ct], s0);
                    s1 = fmaf(v, w31[ct], s1);
                    s2 = fmaf(v, w32[ct], s2);
                }
                #pragma unroll
                for (int off = 1; off < 16; off <<= 1) {
                    s0 += __shfl_xor(s0, off);
                    s1 += __shfl_xor(s1, off);
                    s2 += __shfl_xor(s2, off);
                }
                if (lr == 0) {
                    const int pt = wr*64 + rt*16 + lk*4 + r;
                    const int base = FB_PRGB_OFF/4 + (wc*128 + pt)*3;
                    smf[base + 0] = s0;
                    smf[base + 1] = s1;
                    smf[base + 2] = s2;
                }
            }
    }
    __syncthreads();
    if (tid < 128) {
        const int p = tid;
        const float s0 = smf[p*3 + 0] + smf[(128 + p)*3 + 0] + g_b3[0];
        const float s1 = smf[p*3 + 1] + smf[(128 + p)*3 + 1] + g_b3[1];
        const float s2 = smf[p*3 + 2] + smf[(128 + p)*3 + 2] + g_b3[2];
        const int pt = ray*128 + p;
        out_rgb[pt*3 + 0] = 1.0f / (1.0f + expf(-s0));
        out_rgb[pt*3 + 1] = 1.0f / (1.0f + expf(-s1));
        out_rgb[pt*3 + 2] = 1.0f / (1.0f + expf(-s2));
    }
}

extern "C" void kernel_launch(void* const* d_in, const int* in_sizes, int n_in,
                              void* d_out, int out_size, void* d_ws, size_t ws_size,
                              hipStream_t stream)
{
    const float* g_org = (const float*)d_in[0];
    const float* g_dir = (const float*)d_in[1];
    const float* g_len = (const float*)d_in[2];
    const float* g_gd  = (const float*)d_in[3];
    const float* g_gc  = (const float*)d_in[4];
    const float* g_w1  = (const float*)d_in[5];
    const float* g_b1  = (const float*)d_in[6];
    const float* g_w2  = (const float*)d_in[7];
    const float* g_b2  = (const float*)d_in[8];
    const float* g_w3  = (const float*)d_in[9];
    const float* g_b3  = (const float*)d_in[10];
    float* out = (float*)d_out;

    if (ws_size >= NEED_FULL) {
        __bf16* wsb  = (__bf16*)d_ws;
        float*  b1r  = (float*)((char*)d_ws + B1R_B);
        bf16x8* pack = (bf16x8*)((char*)d_ws + PACK2_B);
        dvgo_prep2<<<6043, 256, 0, stream>>>(g_gd, g_gc, g_w1, g_w2, g_w3, g_dir,
                                             g_b1, pack, wsb, b1r);
        dvgo_mlp<<<4096, 256, 0, stream>>>((const bf16x8*)wsb, b1r, pack,
                                           g_org, g_dir, g_len,
                                           g_b2, g_b3, out, out + 4096*128);
    } else if (ws_size >= NEED_PACK) {
        __bf16* wsb  = (__bf16*)d_ws;
        bf16x8* pack = (bf16x8*)((char*)d_ws + EMB_B);
        dvgo_prep_fb<<<4011, 256, 0, stream>>>(g_gd, g_gc, g_w1, g_w2, g_w3, g_dir,
                                               pack, wsb, 3907);
        dvgo_main<true><<<4096, 256, 0, stream>>>(g_org, g_dir, g_len, g_gd, g_gc,
                                                  g_b1, g_b2, g_w3, g_b3,
                                                  (const bf16x8*)wsb, pack,
                                                  out, out + 4096*128);
    } else {
        __bf16* wsb = (__bf16*)d_ws;
        dvgo_prep_fb<<<104, 256, 0, stream>>>(g_gd, g_gc, g_w1, g_w2, g_w3, g_dir,
                                              (bf16x8*)d_ws, wsb, 0);
        dvgo_main<false><<<4096, 256, 0, stream>>>(g_org, g_dir, g_len, g_gd, g_gc,
                                                   g_b1, g_b2, g_w3, g_b3,
                                                   (const bf16x8*)wsb, nullptr,
                                                   out, out + 4096*128);
    }
}

// Round 14
// 71.905 us; speedup vs baseline: 1.6828x; 1.0188x over previous
//
#include <hip/hip_runtime.h>
#include <hip/hip_bf16.h>
#include <math.h>

// DirectVoxGO fused forward, v14.
// = v13 (gather fused into zero-barrier MLP; prep2 grid-pack + weight frags +
//   per-ray f32 bias) with ONE change: dvgo_mlp launch_bounds (256,4)->(256,3).
//   r13 showed WRITE_SIZE 38.7MB vs 8.4MB outputs = ~8 dwords/thread scratch
//   spill from holding aw1[8]+gather state under the 128-reg cap; measured
//   occupancy (35%) was already below the 16-wave cap, so (256,3) removes the
//   spill at ~zero occupancy cost.

typedef __bf16 bf16x4 __attribute__((ext_vector_type(4)));
typedef __bf16 bf16x8 __attribute__((ext_vector_type(8)));
typedef float  f32x4  __attribute__((ext_vector_type(4)));

#define ACT_SHIFT_F (-13.815509557964774f)

// ---- full-path ws layout (bytes) ----
#define B1R_B   45056
#define PACK2_B 2142208
#define NEED_FULL 34142208ull     // pack end (no feat region)

// ---- fallback ws layout (old, unchanged) ----
#define EMB_B   53248
#define PACK_B  315392
#define NEED_PACK 32315392ull

// ================= prep2 (full path) =================
__global__ __launch_bounds__(256)
void dvgo_prep2(const float* __restrict__ g_gd, const float* __restrict__ g_gc,
                const float* __restrict__ g_w1, const float* __restrict__ g_w2,
                const float* __restrict__ g_w3, const float* __restrict__ g_dir,
                const float* __restrict__ g_b1,
                bf16x8* __restrict__ pack, __bf16* __restrict__ wsb,
                float* __restrict__ b1r)
{
    const int bid = blockIdx.x;
    const int tid = threadIdx.x;
    if (bid < 3907) {
        const int gi = bid * 256 + tid;
        if (gi >= 1000000) return;
        bf16x8 v0, v1;
        #pragma unroll
        for (int c = 0; c < 8; ++c) v0[c] = (__bf16)g_gc[c * 1000000 + gi];
        #pragma unroll
        for (int c = 0; c < 4; ++c) v1[c] = (__bf16)g_gc[(8 + c) * 1000000 + gi];
        v1[4] = (__bf16)g_gd[gi];
        v1[5] = (__bf16)0.0f; v1[6] = (__bf16)0.0f; v1[7] = (__bf16)0.0f;
        pack[gi * 2 + 0] = v0;
        pack[gi * 2 + 1] = v1;
        return;
    }
    const int idx2 = bid - 3907;
    if (idx2 < 88) {
        const int idx = idx2 * 256 + tid;
        if (idx < 4096) {                       // w1 A-frags, K=32, k>=12 zero
            const int j = idx & 7, lane = (idx >> 3) & 63, ct = idx >> 9;
            const int n = ct * 16 + (lane & 15);
            const int k = ((lane >> 4) & 3) * 8 + j;
            wsb[idx] = (__bf16)((k < 12) ? g_w1[k * 128 + n] : 0.0f);
        } else if (idx < 20480) {               // w2 A-frags
            const int i2 = idx - 4096;
            const int j = i2 & 7, lane = (i2 >> 3) & 63, ks = (i2 >> 9) & 3, ct = i2 >> 11;
            const int n = ct * 16 + (lane & 15);
            const int k = ks * 32 + ((lane >> 4) & 3) * 8 + j;
            wsb[idx] = (__bf16)g_w2[k * 128 + n];
        } else if (idx < 22528) {               // w3 A-frags, cols >=3 zero
            const int i3 = idx - 20480;
            const int j = i3 & 7, lane = (i3 >> 3) & 63, ks = i3 >> 9;
            const int c = lane & 15;
            const int k = ks * 32 + ((lane >> 4) & 3) * 8 + j;
            wsb[idx] = (__bf16)((c < 3) ? g_w3[k * 3 + c] : 0.0f);
        }
        return;
    }
    // b1r: b1 + emb27 . w1[12:39,:]
    const int rr  = idx2 - 88;
    const int ray = rr * 2 + (tid >> 7);
    const int n   = tid & 127;
    const float d0 = g_dir[ray*3+0], d1 = g_dir[ray*3+1], d2 = g_dir[ray*3+2];
    float s = g_b1[n];
    s += d0 * g_w1[12*128 + n] + d1 * g_w1[13*128 + n] + d2 * g_w1[14*128 + n];
    #pragma unroll
    for (int m = 0; m < 12; ++m) {
        const int i = m >> 2, j = m & 3;
        const float di = (i == 0) ? d0 : ((i == 1) ? d1 : d2);
        const float a = di * (float)(1 << j);
        s += sinf(a) * g_w1[(15 + m)*128 + n];
        s += cosf(a) * g_w1[(27 + m)*128 + n];
    }
    b1r[ray*128 + n] = s;
}

// ================= M: fused gather + MLP (zero barriers) =================
__global__ __launch_bounds__(256, 3)
void dvgo_mlp(const bf16x8* __restrict__ wf, const float* __restrict__ b1r,
              const bf16x8* __restrict__ pack,
              const float* __restrict__ g_org, const float* __restrict__ g_dir,
              const float* __restrict__ g_len,
              const float* __restrict__ g_b2, const float* __restrict__ g_b3,
              float* __restrict__ out_alpha, float* __restrict__ out_rgb)
{
    __shared__ __align__(16) char smem[32768];   // 4 wave-private 8KB slabs
    const int tid  = threadIdx.x;
    const int ray  = blockIdx.x;
    const int lane = tid & 63;
    const int wid  = tid >> 6;
    const int lr   = lane & 15;
    const int lk   = lane >> 4;
    const int sz   = (lr & 7) << 4;
    char* slab = smem + wid*8192;

    // ---- prefetch GEMM1 weights at entry (land during gather) ----
    bf16x8 aw1[8];
    #pragma unroll
    for (int ct = 0; ct < 8; ++ct) aw1[ct] = wf[ct*64 + lane];

    // ================= gather phase: 2 lanes/pt, dz split =================
    {
        const int p    = wid*32 + (lane & 31);    // own point within ray
        const int dzv  = lane >> 5;
        const float d0 = g_dir[ray*3+0], d1 = g_dir[ray*3+1], d2 = g_dir[ray*3+2];
        const float o0 = g_org[ray*3+0], o1 = g_org[ray*3+1], o2 = g_org[ray*3+2];
        const float len = g_len[ray*128 + p];

        const float px = (o0 + d0*len + 1.0f) * 49.5f;
        const float py = (o1 + d1*len + 1.0f) * 49.5f;
        const float pz = (o2 + d2*len + 1.0f) * 49.5f;
        const float fx = floorf(px), fy = floorf(py), fz = floorf(pz);
        const int ix = (int)fx, iy = (int)fy, iz0 = (int)fz;
        const float qx = px - fx, qy = py - fy, qz = pz - fz;
        const float wxa[2] = {1.0f - qx, qx};
        const float wya[2] = {1.0f - qy, qy};
        const int  cxa[2] = {min(max(ix,0),99),   min(max(ix+1,0),99)};
        const int  cya[2] = {min(max(iy,0),99),   min(max(iy+1,0),99)};
        const bool vxa[2] = {(unsigned)ix < 100u, (unsigned)(ix+1) < 100u};
        const bool vya[2] = {(unsigned)iy < 100u, (unsigned)(iy+1) < 100u};
        const int  iz = iz0 + dzv;
        const float wz = dzv ? qz : (1.0f - qz);
        const int  cz = min(max(iz,0),99);
        const bool vz = (unsigned)iz < 100u;

        float den = 0.0f;
        float cc[12];
        #pragma unroll
        for (int c = 0; c < 12; ++c) cc[c] = 0.0f;

        #pragma unroll
        for (int dy = 0; dy < 2; ++dy)
        #pragma unroll
        for (int dx = 0; dx < 2; ++dx) {
            float w = wxa[dx] * wya[dy] * wz;
            if (!(vxa[dx] && vya[dy] && vz)) w = 0.0f;
            const int gi = (cz*100 + cya[dy])*100 + cxa[dx];
            const bf16x8 v0 = pack[gi*2 + 0];
            const bf16x8 v1 = pack[gi*2 + 1];
            #pragma unroll
            for (int c = 0; c < 8; ++c) cc[c]     += w * (float)v0[c];
            #pragma unroll
            for (int c = 0; c < 4; ++c) cc[8 + c] += w * (float)v1[c];
            den += w * (float)v1[4];
        }

        // combine dz halves (lane ^ 32)
        #pragma unroll
        for (int c = 0; c < 12; ++c) cc[c] += __shfl_xor(cc[c], 32);
        den += __shfl_xor(den, 32);

        if (dzv == 0) {
            const float interval = sqrtf(d0*d0 + d1*d1 + d2*d2);
            const float e = expf(den + ACT_SHIFT_F);
            out_alpha[ray*128 + p] = -expm1f(-interval * log1pf(e));
            // stage feat -> own slab [pt&31][32B]: ch0-7 | ch8-11 + zero pad
            bf16x8 f0, f1;
            #pragma unroll
            for (int c = 0; c < 8; ++c) f0[c] = (__bf16)cc[c];
            #pragma unroll
            for (int c = 0; c < 4; ++c) f1[c] = (__bf16)cc[8 + c];
            #pragma unroll
            for (int c = 4; c < 8; ++c) f1[c] = (__bf16)0.0f;
            *(bf16x8*)(slab + (lane & 31)*32 +  0) = f0;
            *(bf16x8*)(slab + (lane & 31)*32 + 16) = f1;
        }
    }

    // ---- feat B-frags from own slab (consumed before h1 overwrites) ----
    bf16x8 zed;
    #pragma unroll
    for (int j = 0; j < 8; ++j) zed[j] = (__bf16)0.0f;
    bf16x8 bb[2];
    #pragma unroll
    for (int q = 0; q < 2; ++q) {
        const bf16x8 t = *(const bf16x8*)(slab + (q*16 + lr)*32 + (lk & 1)*16);
        bb[q] = (lk < 2) ? t : zed;
    }

    const int rowb = (wid*32 + lr)*256;
    int rb2[4];
    #pragma unroll
    for (int ks = 0; ks < 4; ++ks)
        rb2[ks] = rowb + ((ks*64 + lk*16) ^ sz);

    // ---- GEMM1 (pt-slice): own 32 pts x all 128 n1; h1 -> own slab ----
    #pragma unroll
    for (int ct = 0; ct < 8; ++ct) {
        f32x4 a0 = (f32x4){0.f,0.f,0.f,0.f};
        f32x4 a1 = (f32x4){0.f,0.f,0.f,0.f};
        a0 = __builtin_amdgcn_mfma_f32_16x16x32_bf16(aw1[ct], bb[0], a0, 0, 0, 0);
        a1 = __builtin_amdgcn_mfma_f32_16x16x32_bf16(aw1[ct], bb[1], a1, 0, 0, 0);
        const f32x4 b1v = *(const f32x4*)(b1r + ray*128 + ct*16 + lk*4);
        bf16x4 h0, h1;
        #pragma unroll
        for (int r = 0; r < 4; ++r) {
            h0[r] = (__bf16)fmaxf(a0[r] + b1v[r], 0.0f);
            h1[r] = (__bf16)fmaxf(a1[r] + b1v[r], 0.0f);
        }
        const int csw = (ct*32 + lk*8) ^ sz;
        *(bf16x4*)(smem + rowb + csw) = h0;
        *(bf16x4*)(smem + rowb + 4096 + csw) = h1;
    }

    // ---- GEMM2 (pt-slice): read own h1 (all k) then overwrite slab with h2 ----
    bf16x8 hq[2][4];
    #pragma unroll
    for (int q = 0; q < 2; ++q)
        #pragma unroll
        for (int ks = 0; ks < 4; ++ks)
            hq[q][ks] = *(const bf16x8*)(smem + rb2[ks] + q*4096);

    #pragma unroll
    for (int ct = 0; ct < 8; ++ct) {
        bf16x8 aw2[4];
        #pragma unroll
        for (int ks = 0; ks < 4; ++ks)
            aw2[ks] = wf[512 + (ct*4 + ks)*64 + lane];
        f32x4 a0 = (f32x4){0.f,0.f,0.f,0.f};
        f32x4 a1 = (f32x4){0.f,0.f,0.f,0.f};
        #pragma unroll
        for (int ks = 0; ks < 4; ++ks) {
            a0 = __builtin_amdgcn_mfma_f32_16x16x32_bf16(aw2[ks], hq[0][ks], a0, 0, 0, 0);
            a1 = __builtin_amdgcn_mfma_f32_16x16x32_bf16(aw2[ks], hq[1][ks], a1, 0, 0, 0);
        }
        const f32x4 b2v = *(const f32x4*)(g_b2 + ct*16 + lk*4);
        bf16x4 h0, h1;
        #pragma unroll
        for (int r = 0; r < 4; ++r) {
            h0[r] = (__bf16)fmaxf(a0[r] + b2v[r], 0.0f);
            h1[r] = (__bf16)fmaxf(a1[r] + b2v[r], 0.0f);
        }
        const int csw = (ct*32 + lk*8) ^ sz;
        *(bf16x4*)(smem + rowb + csw) = h0;
        *(bf16x4*)(smem + rowb + 4096 + csw) = h1;
    }

    // ---- GEMM3: own 2 pt-tiles, w3 padded to 16 cols ----
    bf16x8 aw3[4];
    #pragma unroll
    for (int ks = 0; ks < 4; ++ks) aw3[ks] = wf[2560 + ks*64 + lane];
    f32x4 acc3[2];
    acc3[0] = (f32x4){0.f,0.f,0.f,0.f};
    acc3[1] = (f32x4){0.f,0.f,0.f,0.f};
    #pragma unroll
    for (int q = 0; q < 2; ++q)
        #pragma unroll
        for (int ks = 0; ks < 4; ++ks) {
            const bf16x8 hq3 = *(const bf16x8*)(smem + rb2[ks] + q*4096);
            acc3[q] = __builtin_amdgcn_mfma_f32_16x16x32_bf16(aw3[ks], hq3, acc3[q], 0, 0, 0);
        }

    // ---- sigmoid -> wave-private LDS staging -> coalesced store ----
    float* smf = (float*)slab;
    if (lk == 0) {
        const float b30 = g_b3[0], b31 = g_b3[1], b32 = g_b3[2];
        #pragma unroll
        for (int q = 0; q < 2; ++q) {
            const int o = (q*16 + lr)*3;
            smf[o + 0] = 1.0f / (1.0f + __expf(-(acc3[q][0] + b30)));
            smf[o + 1] = 1.0f / (1.0f + __expf(-(acc3[q][1] + b31)));
            smf[o + 2] = 1.0f / (1.0f + __expf(-(acc3[q][2] + b32)));
        }
    }
    asm volatile("s_waitcnt lgkmcnt(0)");
    __builtin_amdgcn_sched_barrier(0);
    {
        const int base = (ray*128 + wid*32)*3;
        out_rgb[base + lane] = smf[lane];
        if (lane < 32) out_rgb[base + 64 + lane] = smf[64 + lane];
    }
}

// ================= fallback prep (old layout) + fused kernel (v3) =================
__global__ __launch_bounds__(256)
void dvgo_prep_fb(const float* __restrict__ g_gd, const float* __restrict__ g_gc,
                  const float* __restrict__ g_w1, const float* __restrict__ g_w2,
                  const float* __restrict__ g_w3, const float* __restrict__ g_dir,
                  bf16x8* __restrict__ pack, __bf16* __restrict__ wsb, int wbase)
{
    const int bid = blockIdx.x;
    if (bid < wbase) {
        const int gi = bid * 256 + threadIdx.x;
        if (gi >= 1000000) return;
        bf16x8 v0, v1;
        #pragma unroll
        for (int c = 0; c < 8; ++c) v0[c] = (__bf16)g_gc[c * 1000000 + gi];
        #pragma unroll
        for (int c = 0; c < 4; ++c) v1[c] = (__bf16)g_gc[(8 + c) * 1000000 + gi];
        v1[4] = (__bf16)g_gd[gi];
        v1[5] = (__bf16)0.0f; v1[6] = (__bf16)0.0f; v1[7] = (__bf16)0.0f;
        pack[gi * 2 + 0] = v0;
        pack[gi * 2 + 1] = v1;
        return;
    }
    const int idx = (bid - wbase) * 256 + threadIdx.x;
    if (idx < 8192) {
        const int j = idx & 7, lane = (idx >> 3) & 63, ks = (idx >> 9) & 1, ct = idx >> 10;
        const int n = ct * 16 + (lane & 15);
        const int k = ks * 32 + ((lane >> 4) & 3) * 8 + j;
        wsb[idx] = (__bf16)((k < 39) ? g_w1[k * 128 + n] : 0.0f);
    } else if (idx < 24576) {
        const int i2 = idx - 8192;
        const int j = i2 & 7, lane = (i2 >> 3) & 63, ks = (i2 >> 9) & 3, ct = i2 >> 11;
        const int n = ct * 16 + (lane & 15);
        const int k = ks * 32 + ((lane >> 4) & 3) * 8 + j;
        wsb[idx] = (__bf16)g_w2[k * 128 + n];
    }
}

#define FB_FEAT_OFF 0
#define FB_PCC_OFF  16384
#define FB_H1_OFF   0
#define FB_PRGB_OFF 0

template <bool PACKED>
__global__ __launch_bounds__(256, 4)
void dvgo_main(const float* __restrict__ g_org, const float* __restrict__ g_dir,
               const float* __restrict__ g_len, const float* __restrict__ g_gd,
               const float* __restrict__ g_gc, const float* __restrict__ g_b1,
               const float* __restrict__ g_b2, const float* __restrict__ g_w3,
               const float* __restrict__ g_b3, const bf16x8* __restrict__ wf,
               const bf16x8* __restrict__ g_pack,
               float* __restrict__ out_alpha, float* __restrict__ out_rgb)
{
    __shared__ __align__(16) char smem[32768];
    float* smf = (float*)smem;
    const int tid = threadIdx.x;
    const int ray = blockIdx.x;
    const float d0 = g_dir[ray*3+0], d1 = g_dir[ray*3+1], d2 = g_dir[ray*3+2];
    {
        const float o0 = g_org[ray*3+0], o1 = g_org[ray*3+1], o2 = g_org[ray*3+2];
        const int p = tid & 127;
        const int dzv = tid >> 7;
        const float len = g_len[ray*128 + p];
        const float px = (o0 + d0*len + 1.0f) * 49.5f;
        const float py = (o1 + d1*len + 1.0f) * 49.5f;
        const float pz = (o2 + d2*len + 1.0f) * 49.5f;
        const float fx = floorf(px), fy = floorf(py), fz = floorf(pz);
        const int ix = (int)fx, iy = (int)fy, iz0 = (int)fz;
        const float qx = px - fx, qy = py - fy, qz = pz - fz;
        const float wxa[2] = {1.0f - qx, qx};
        const float wya[2] = {1.0f - qy, qy};
        const int  cxa[2] = {min(max(ix,0),99),   min(max(ix+1,0),99)};
        const int  cya[2] = {min(max(iy,0),99),   min(max(iy+1,0),99)};
        const bool vxa[2] = {(unsigned)ix < 100u, (unsigned)(ix+1) < 100u};
        const bool vya[2] = {(unsigned)iy < 100u, (unsigned)(iy+1) < 100u};
        const int  iz = iz0 + dzv;
        const float wz = dzv ? qz : (1.0f - qz);
        const int  cz = min(max(iz,0),99);
        const bool vz = (unsigned)iz < 100u;
        float den = 0.0f;
        float cc[12];
        #pragma unroll
        for (int c = 0; c < 12; ++c) cc[c] = 0.0f;
        #pragma unroll
        for (int dy = 0; dy < 2; ++dy)
        #pragma unroll
        for (int dx = 0; dx < 2; ++dx) {
            float w = wxa[dx] * wya[dy] * wz;
            if (!(vxa[dx] && vya[dy] && vz)) w = 0.0f;
            const int gi = (cz*100 + cya[dy])*100 + cxa[dx];
            if (PACKED) {
                const bf16x8 v0 = g_pack[gi*2 + 0];
                const bf16x8 v1 = g_pack[gi*2 + 1];
                #pragma unroll
                for (int c = 0; c < 8; ++c) cc[c]     += w * (float)v0[c];
                #pragma unroll
                for (int c = 0; c < 4; ++c) cc[8 + c] += w * (float)v1[c];
                den += w * (float)v1[4];
            } else {
                den += w * g_gd[gi];
                #pragma unroll
                for (int c = 0; c < 12; ++c) cc[c] += w * g_gc[c*1000000 + gi];
            }
        }
        if (dzv) {
            #pragma unroll
            for (int c = 0; c < 12; ++c) smf[FB_PCC_OFF/4 + p*13 + c] = cc[c];
            smf[FB_PCC_OFF/4 + p*13 + 12] = den;
        }
        __syncthreads();
        if (!dzv) {
            #pragma unroll
            for (int c = 0; c < 12; ++c) cc[c] += smf[FB_PCC_OFF/4 + p*13 + c];
            den += smf[FB_PCC_OFF/4 + p*13 + 12];
            const float interval = sqrtf(d0*d0 + d1*d1 + d2*d2);
            const float e = expf(den + ACT_SHIFT_F);
            out_alpha[ray*128 + p] = -expm1f(-interval * log1pf(e));
            bf16x8 f0; bf16x4 f1;
            #pragma unroll
            for (int c = 0; c < 8; ++c) f0[c] = (__bf16)cc[c];
            #pragma unroll
            for (int c = 0; c < 4; ++c) f1[c] = (__bf16)cc[8+c];
            const int swz = (p & 7) << 4;
            *reinterpret_cast<bf16x8*>(smem + ((FB_FEAT_OFF + p*128 +  0) ^ swz)) = f0;
            *reinterpret_cast<bf16x4*>(smem + ((FB_FEAT_OFF + p*128 + 16) ^ swz)) = f1;
        } else {
            float vals[52];
            vals[0] = d0; vals[1] = d1; vals[2] = d2;
            #pragma unroll
            for (int i = 0; i < 3; ++i) {
                const float di = (i == 0) ? d0 : ((i == 1) ? d1 : d2);
                #pragma unroll
                for (int j = 0; j < 4; ++j) {
                    const float a = di * (float)(1 << j);
                    vals[3  + i*4 + j] = sinf(a);
                    vals[15 + i*4 + j] = cosf(a);
                }
            }
            #pragma unroll
            for (int c = 27; c < 52; ++c) vals[c] = 0.0f;
            const int swz = (p & 7) << 4;
            #pragma unroll
            for (int i = 0; i < 13; ++i) {
                bf16x4 v4;
                #pragma unroll
                for (int r = 0; r < 4; ++r) v4[r] = (__bf16)vals[i*4 + r];
                *reinterpret_cast<bf16x4*>(smem + ((FB_FEAT_OFF + p*128 + 24 + i*8) ^ swz)) = v4;
            }
        }
    }
    __syncthreads();
    const int lane = tid & 63;
    const int wid  = tid >> 6;
    const int lr   = lane & 15;
    const int lk   = lane >> 4;
    {
        bf16x8 bf[2][2];
        #pragma unroll
        for (int rt = 0; rt < 2; ++rt)
            #pragma unroll
            for (int ks = 0; ks < 2; ++ks) {
                const int pt = wid*32 + rt*16 + lr;
                int a = FB_FEAT_OFF + pt*128 + ks*64 + lk*16; a ^= (pt & 7) << 4;
                bf[rt][ks] = *reinterpret_cast<const bf16x8*>(smem + a);
            }
        __syncthreads();
        f32x4 acc1[2][8];
        #pragma unroll
        for (int rt = 0; rt < 2; ++rt)
            #pragma unroll
            for (int ct = 0; ct < 8; ++ct) acc1[rt][ct] = (f32x4){0.f,0.f,0.f,0.f};
        #pragma unroll
        for (int ct = 0; ct < 8; ++ct) {
            const bf16x8 aw0 = wf[(ct*2 + 0)*64 + lane];
            const bf16x8 aw1 = wf[(ct*2 + 1)*64 + lane];
            #pragma unroll
            for (int rt = 0; rt < 2; ++rt) {
                acc1[rt][ct] = __builtin_amdgcn_mfma_f32_16x16x32_bf16(aw0, bf[rt][0], acc1[rt][ct], 0, 0, 0);
                acc1[rt][ct] = __builtin_amdgcn_mfma_f32_16x16x32_bf16(aw1, bf[rt][1], acc1[rt][ct], 0, 0, 0);
            }
        }
        #pragma unroll
        for (int ct = 0; ct < 8; ++ct) {
            const f32x4 b1v = *reinterpret_cast<const f32x4*>(g_b1 + ct*16 + lk*4);
            #pragma unroll
            for (int rt = 0; rt < 2; ++rt) {
                const int pt = wid*32 + rt*16 + lr;
                bf16x4 hv;
                #pragma unroll
                for (int r = 0; r < 4; ++r)
                    hv[r] = (__bf16)fmaxf(acc1[rt][ct][r] + b1v[r], 0.0f);
                int a = FB_H1_OFF + pt*256 + ct*32 + lk*8; a ^= (pt & 7) << 4;
                *reinterpret_cast<bf16x4*>(smem + a) = hv;
            }
        }
    }
    __syncthreads();
    const int wr = wid >> 1, wc = wid & 1;
    f32x4 acc2[4][4];
    #pragma unroll
    for (int rt = 0; rt < 4; ++rt)
        #pragma unroll
        for (int ct = 0; ct < 4; ++ct) acc2[rt][ct] = (f32x4){0.f,0.f,0.f,0.f};
    #pragma unroll
    for (int ks = 0; ks < 4; ++ks) {
        bf16x8 a2[4];
        #pragma unroll
        for (int rt = 0; rt < 4; ++rt) {
            const int pt = wr*64 + rt*16 + lr;
            int a = FB_H1_OFF + pt*256 + ks*64 + lk*16; a ^= (pt & 7) << 4;
            a2[rt] = *reinterpret_cast<const bf16x8*>(smem + a);
        }
        #pragma unroll
        for (int ct = 0; ct < 4; ++ct) {
            const int ctg = wc*4 + ct;
            const bf16x8 b2f = wf[1024 + (ctg*4 + ks)*64 + lane];
            #pragma unroll
            for (int rt = 0; rt < 4; ++rt)
                acc2[rt][ct] = __builtin_amdgcn_mfma_f32_16x16x32_bf16(a2[rt], b2f, acc2[rt][ct], 0, 0, 0);
        }
    }
    __syncthreads();
    {
        float b2v[4], w30[4], w31[4], w32[4];
        #pragma unroll
        for (int ct = 0; ct < 4; ++ct) {
            const int n2 = wc*64 + ct*16 + lr;
            b2v[ct] = g_b2[n2];
            w30[ct] = g_w3[n2*3 + 0];
            w31[ct] = g_w3[n2*3 + 1];
            w32[ct] = g_w3[n2*3 + 2];
        }
        #pragma unroll
        for (int rt = 0; rt < 4; ++rt)
            #pragma unroll
            for (int r = 0; r < 4; ++r) {
                float s0 = 0.f, s1 = 0.f, s2 = 0.f;
                #pragma unroll
                for (int ct = 0; ct < 4; ++ct) {
                    const float v = fmaxf(acc2[rt][ct][r] + b2v[ct], 0.0f);
                    s0 = fmaf(v, w30[ct], s0);
                    s1 = fmaf(v, w31[ct], s1);
                    s2 = fmaf(v, w32[ct], s2);
                }
                #pragma unroll
                for (int off = 1; off < 16; off <<= 1) {
                    s0 += __shfl_xor(s0, off);
                    s1 += __shfl_xor(s1, off);
                    s2 += __shfl_xor(s2, off);
                }
                if (lr == 0) {
                    const int pt = wr*64 + rt*16 + lk*4 + r;
                    const int base = FB_PRGB_OFF/4 + (wc*128 + pt)*3;
                    smf[base + 0] = s0;
                    smf[base + 1] = s1;
                    smf[base + 2] = s2;
                }
            }
    }
    __syncthreads();
    if (tid < 128) {
        const int p = tid;
        const float s0 = smf[p*3 + 0] + smf[(128 + p)*3 + 0] + g_b3[0];
        const float s1 = smf[p*3 + 1] + smf[(128 + p)*3 + 1] + g_b3[1];
        const float s2 = smf[p*3 + 2] + smf[(128 + p)*3 + 2] + g_b3[2];
        const int pt = ray*128 + p;
        out_rgb[pt*3 + 0] = 1.0f / (1.0f + expf(-s0));
        out_rgb[pt*3 + 1] = 1.0f / (1.0f + expf(-s1));
        out_rgb[pt*3 + 2] = 1.0f / (1.0f + expf(-s2));
    }
}

extern "C" void kernel_launch(void* const* d_in, const int* in_sizes, int n_in,
                              void* d_out, int out_size, void* d_ws, size_t ws_size,
                              hipStream_t stream)
{
    const float* g_org = (const float*)d_in[0];
    const float* g_dir = (const float*)d_in[1];
    const float* g_len = (const float*)d_in[2];
    const float* g_gd  = (const float*)d_in[3];
    const float* g_gc  = (const float*)d_in[4];
    const float* g_w1  = (const float*)d_in[5];
    const float* g_b1  = (const float*)d_in[6];
    const float* g_w2  = (const float*)d_in[7];
    const float* g_b2  = (const float*)d_in[8];
    const float* g_w3  = (const float*)d_in[9];
    const float* g_b3  = (const float*)d_in[10];
    float* out = (float*)d_out;

    if (ws_size >= NEED_FULL) {
        __bf16* wsb  = (__bf16*)d_ws;
        float*  b1r  = (float*)((char*)d_ws + B1R_B);
        bf16x8* pack = (bf16x8*)((char*)d_ws + PACK2_B);
        dvgo_prep2<<<6043, 256, 0, stream>>>(g_gd, g_gc, g_w1, g_w2, g_w3, g_dir,
                                             g_b1, pack, wsb, b1r);
        dvgo_mlp<<<4096, 256, 0, stream>>>((const bf16x8*)wsb, b1r, pack,
                                           g_org, g_dir, g_len,
                                           g_b2, g_b3, out, out + 4096*128);
    } else if (ws_size >= NEED_PACK) {
        __bf16* wsb  = (__bf16*)d_ws;
        bf16x8* pack = (bf16x8*)((char*)d_ws + EMB_B);
        dvgo_prep_fb<<<4011, 256, 0, stream>>>(g_gd, g_gc, g_w1, g_w2, g_w3, g_dir,
                                               pack, wsb, 3907);
        dvgo_main<true><<<4096, 256, 0, stream>>>(g_org, g_dir, g_len, g_gd, g_gc,
                                                  g_b1, g_b2, g_w3, g_b3,
                                                  (const bf16x8*)wsb, pack,
                                                  out, out + 4096*128);
    } else {
        __bf16* wsb = (__bf16*)d_ws;
        dvgo_prep_fb<<<104, 256, 0, stream>>>(g_gd, g_gc, g_w1, g_w2, g_w3, g_dir,
                                              (bf16x8*)d_ws, wsb, 0);
        dvgo_main<false><<<4096, 256, 0, stream>>>(g_org, g_dir, g_len, g_gd, g_gc,
                                                   g_b1, g_b2, g_w3, g_b3,
                                                   (const bf16x8*)wsb, nullptr,
                                                   out, out + 4096*128);
    }
}

// Round 15
// 70.153 us; speedup vs baseline: 1.7248x; 1.0250x over previous
//
#include <hip/hip_runtime.h>
#include <hip/hip_bf16.h>
#include <math.h>

// DirectVoxGO fused forward, v15.
// = v14 (gather fused into zero-barrier MLP) with register-budget fix:
//   aw1 entry-prefetch REMOVED (was 32 VGPRs live across gather = r13's spill);
//   aw1[ct] now loads inside the GEMM1 ct-loop (same pattern as aw2, which
//   never spilled). launch_bounds back to (256,4): r14 proved no-spill and
//   r13 proved 4-blocks occupancy are each worth ~6us -- this stacks both.

typedef __bf16 bf16x4 __attribute__((ext_vector_type(4)));
typedef __bf16 bf16x8 __attribute__((ext_vector_type(8)));
typedef float  f32x4  __attribute__((ext_vector_type(4)));

#define ACT_SHIFT_F (-13.815509557964774f)

// ---- full-path ws layout (bytes) ----
#define B1R_B   45056
#define PACK2_B 2142208
#define NEED_FULL 34142208ull     // pack end (no feat region)

// ---- fallback ws layout (old, unchanged) ----
#define EMB_B   53248
#define PACK_B  315392
#define NEED_PACK 32315392ull

// ================= prep2 (full path) =================
__global__ __launch_bounds__(256)
void dvgo_prep2(const float* __restrict__ g_gd, const float* __restrict__ g_gc,
                const float* __restrict__ g_w1, const float* __restrict__ g_w2,
                const float* __restrict__ g_w3, const float* __restrict__ g_dir,
                const float* __restrict__ g_b1,
                bf16x8* __restrict__ pack, __bf16* __restrict__ wsb,
                float* __restrict__ b1r)
{
    const int bid = blockIdx.x;
    const int tid = threadIdx.x;
    if (bid < 3907) {
        const int gi = bid * 256 + tid;
        if (gi >= 1000000) return;
        bf16x8 v0, v1;
        #pragma unroll
        for (int c = 0; c < 8; ++c) v0[c] = (__bf16)g_gc[c * 1000000 + gi];
        #pragma unroll
        for (int c = 0; c < 4; ++c) v1[c] = (__bf16)g_gc[(8 + c) * 1000000 + gi];
        v1[4] = (__bf16)g_gd[gi];
        v1[5] = (__bf16)0.0f; v1[6] = (__bf16)0.0f; v1[7] = (__bf16)0.0f;
        pack[gi * 2 + 0] = v0;
        pack[gi * 2 + 1] = v1;
        return;
    }
    const int idx2 = bid - 3907;
    if (idx2 < 88) {
        const int idx = idx2 * 256 + tid;
        if (idx < 4096) {                       // w1 A-frags, K=32, k>=12 zero
            const int j = idx & 7, lane = (idx >> 3) & 63, ct = idx >> 9;
            const int n = ct * 16 + (lane & 15);
            const int k = ((lane >> 4) & 3) * 8 + j;
            wsb[idx] = (__bf16)((k < 12) ? g_w1[k * 128 + n] : 0.0f);
        } else if (idx < 20480) {               // w2 A-frags
            const int i2 = idx - 4096;
            const int j = i2 & 7, lane = (i2 >> 3) & 63, ks = (i2 >> 9) & 3, ct = i2 >> 11;
            const int n = ct * 16 + (lane & 15);
            const int k = ks * 32 + ((lane >> 4) & 3) * 8 + j;
            wsb[idx] = (__bf16)g_w2[k * 128 + n];
        } else if (idx < 22528) {               // w3 A-frags, cols >=3 zero
            const int i3 = idx - 20480;
            const int j = i3 & 7, lane = (i3 >> 3) & 63, ks = i3 >> 9;
            const int c = lane & 15;
            const int k = ks * 32 + ((lane >> 4) & 3) * 8 + j;
            wsb[idx] = (__bf16)((c < 3) ? g_w3[k * 3 + c] : 0.0f);
        }
        return;
    }
    // b1r: b1 + emb27 . w1[12:39,:]
    const int rr  = idx2 - 88;
    const int ray = rr * 2 + (tid >> 7);
    const int n   = tid & 127;
    const float d0 = g_dir[ray*3+0], d1 = g_dir[ray*3+1], d2 = g_dir[ray*3+2];
    float s = g_b1[n];
    s += d0 * g_w1[12*128 + n] + d1 * g_w1[13*128 + n] + d2 * g_w1[14*128 + n];
    #pragma unroll
    for (int m = 0; m < 12; ++m) {
        const int i = m >> 2, j = m & 3;
        const float di = (i == 0) ? d0 : ((i == 1) ? d1 : d2);
        const float a = di * (float)(1 << j);
        s += sinf(a) * g_w1[(15 + m)*128 + n];
        s += cosf(a) * g_w1[(27 + m)*128 + n];
    }
    b1r[ray*128 + n] = s;
}

// ================= M: fused gather + MLP (zero barriers) =================
__global__ __launch_bounds__(256, 4)
void dvgo_mlp(const bf16x8* __restrict__ wf, const float* __restrict__ b1r,
              const bf16x8* __restrict__ pack,
              const float* __restrict__ g_org, const float* __restrict__ g_dir,
              const float* __restrict__ g_len,
              const float* __restrict__ g_b2, const float* __restrict__ g_b3,
              float* __restrict__ out_alpha, float* __restrict__ out_rgb)
{
    __shared__ __align__(16) char smem[32768];   // 4 wave-private 8KB slabs
    const int tid  = threadIdx.x;
    const int ray  = blockIdx.x;
    const int lane = tid & 63;
    const int wid  = tid >> 6;
    const int lr   = lane & 15;
    const int lk   = lane >> 4;
    const int sz   = (lr & 7) << 4;
    char* slab = smem + wid*8192;

    // ================= gather phase: 2 lanes/pt, dz split =================
    {
        const int p    = wid*32 + (lane & 31);    // own point within ray
        const int dzv  = lane >> 5;
        const float d0 = g_dir[ray*3+0], d1 = g_dir[ray*3+1], d2 = g_dir[ray*3+2];
        const float o0 = g_org[ray*3+0], o1 = g_org[ray*3+1], o2 = g_org[ray*3+2];
        const float len = g_len[ray*128 + p];

        const float px = (o0 + d0*len + 1.0f) * 49.5f;
        const float py = (o1 + d1*len + 1.0f) * 49.5f;
        const float pz = (o2 + d2*len + 1.0f) * 49.5f;
        const float fx = floorf(px), fy = floorf(py), fz = floorf(pz);
        const int ix = (int)fx, iy = (int)fy, iz0 = (int)fz;
        const float qx = px - fx, qy = py - fy, qz = pz - fz;
        const float wxa[2] = {1.0f - qx, qx};
        const float wya[2] = {1.0f - qy, qy};
        const int  cxa[2] = {min(max(ix,0),99),   min(max(ix+1,0),99)};
        const int  cya[2] = {min(max(iy,0),99),   min(max(iy+1,0),99)};
        const bool vxa[2] = {(unsigned)ix < 100u, (unsigned)(ix+1) < 100u};
        const bool vya[2] = {(unsigned)iy < 100u, (unsigned)(iy+1) < 100u};
        const int  iz = iz0 + dzv;
        const float wz = dzv ? qz : (1.0f - qz);
        const int  cz = min(max(iz,0),99);
        const bool vz = (unsigned)iz < 100u;

        float den = 0.0f;
        float cc[12];
        #pragma unroll
        for (int c = 0; c < 12; ++c) cc[c] = 0.0f;

        #pragma unroll
        for (int dy = 0; dy < 2; ++dy)
        #pragma unroll
        for (int dx = 0; dx < 2; ++dx) {
            float w = wxa[dx] * wya[dy] * wz;
            if (!(vxa[dx] && vya[dy] && vz)) w = 0.0f;
            const int gi = (cz*100 + cya[dy])*100 + cxa[dx];
            const bf16x8 v0 = pack[gi*2 + 0];
            const bf16x8 v1 = pack[gi*2 + 1];
            #pragma unroll
            for (int c = 0; c < 8; ++c) cc[c]     += w * (float)v0[c];
            #pragma unroll
            for (int c = 0; c < 4; ++c) cc[8 + c] += w * (float)v1[c];
            den += w * (float)v1[4];
        }

        // combine dz halves (lane ^ 32)
        #pragma unroll
        for (int c = 0; c < 12; ++c) cc[c] += __shfl_xor(cc[c], 32);
        den += __shfl_xor(den, 32);

        if (dzv == 0) {
            const float interval = sqrtf(d0*d0 + d1*d1 + d2*d2);
            const float e = expf(den + ACT_SHIFT_F);
            out_alpha[ray*128 + p] = -expm1f(-interval * log1pf(e));
            // stage feat -> own slab [pt&31][32B]: ch0-7 | ch8-11 + zero pad
            bf16x8 f0, f1;
            #pragma unroll
            for (int c = 0; c < 8; ++c) f0[c] = (__bf16)cc[c];
            #pragma unroll
            for (int c = 0; c < 4; ++c) f1[c] = (__bf16)cc[8 + c];
            #pragma unroll
            for (int c = 4; c < 8; ++c) f1[c] = (__bf16)0.0f;
            *(bf16x8*)(slab + (lane & 31)*32 +  0) = f0;
            *(bf16x8*)(slab + (lane & 31)*32 + 16) = f1;
        }
    }

    // ---- feat B-frags from own slab (consumed before h1 overwrites) ----
    bf16x8 zed;
    #pragma unroll
    for (int j = 0; j < 8; ++j) zed[j] = (__bf16)0.0f;
    bf16x8 bb[2];
    #pragma unroll
    for (int q = 0; q < 2; ++q) {
        const bf16x8 t = *(const bf16x8*)(slab + (q*16 + lr)*32 + (lk & 1)*16);
        bb[q] = (lk < 2) ? t : zed;
    }

    const int rowb = (wid*32 + lr)*256;
    int rb2[4];
    #pragma unroll
    for (int ks = 0; ks < 4; ++ks)
        rb2[ks] = rowb + ((ks*64 + lk*16) ^ sz);

    // ---- GEMM1 (pt-slice): own 32 pts x all 128 n1; h1 -> own slab ----
    // aw1 loaded per-ct (NOT prefetched across gather -- that was r13's spill)
    #pragma unroll
    for (int ct = 0; ct < 8; ++ct) {
        const bf16x8 aw = wf[ct*64 + lane];
        f32x4 a0 = (f32x4){0.f,0.f,0.f,0.f};
        f32x4 a1 = (f32x4){0.f,0.f,0.f,0.f};
        a0 = __builtin_amdgcn_mfma_f32_16x16x32_bf16(aw, bb[0], a0, 0, 0, 0);
        a1 = __builtin_amdgcn_mfma_f32_16x16x32_bf16(aw, bb[1], a1, 0, 0, 0);
        const f32x4 b1v = *(const f32x4*)(b1r + ray*128 + ct*16 + lk*4);
        bf16x4 h0, h1;
        #pragma unroll
        for (int r = 0; r < 4; ++r) {
            h0[r] = (__bf16)fmaxf(a0[r] + b1v[r], 0.0f);
            h1[r] = (__bf16)fmaxf(a1[r] + b1v[r], 0.0f);
        }
        const int csw = (ct*32 + lk*8) ^ sz;
        *(bf16x4*)(smem + rowb + csw) = h0;
        *(bf16x4*)(smem + rowb + 4096 + csw) = h1;
    }

    // ---- GEMM2 (pt-slice): read own h1 (all k) then overwrite slab with h2 ----
    bf16x8 hq[2][4];
    #pragma unroll
    for (int q = 0; q < 2; ++q)
        #pragma unroll
        for (int ks = 0; ks < 4; ++ks)
            hq[q][ks] = *(const bf16x8*)(smem + rb2[ks] + q*4096);

    #pragma unroll
    for (int ct = 0; ct < 8; ++ct) {
        bf16x8 aw2[4];
        #pragma unroll
        for (int ks = 0; ks < 4; ++ks)
            aw2[ks] = wf[512 + (ct*4 + ks)*64 + lane];
        f32x4 a0 = (f32x4){0.f,0.f,0.f,0.f};
        f32x4 a1 = (f32x4){0.f,0.f,0.f,0.f};
        #pragma unroll
        for (int ks = 0; ks < 4; ++ks) {
            a0 = __builtin_amdgcn_mfma_f32_16x16x32_bf16(aw2[ks], hq[0][ks], a0, 0, 0, 0);
            a1 = __builtin_amdgcn_mfma_f32_16x16x32_bf16(aw2[ks], hq[1][ks], a1, 0, 0, 0);
        }
        const f32x4 b2v = *(const f32x4*)(g_b2 + ct*16 + lk*4);
        bf16x4 h0, h1;
        #pragma unroll
        for (int r = 0; r < 4; ++r) {
            h0[r] = (__bf16)fmaxf(a0[r] + b2v[r], 0.0f);
            h1[r] = (__bf16)fmaxf(a1[r] + b2v[r], 0.0f);
        }
        const int csw = (ct*32 + lk*8) ^ sz;
        *(bf16x4*)(smem + rowb + csw) = h0;
        *(bf16x4*)(smem + rowb + 4096 + csw) = h1;
    }

    // ---- GEMM3: own 2 pt-tiles, w3 padded to 16 cols ----
    bf16x8 aw3[4];
    #pragma unroll
    for (int ks = 0; ks < 4; ++ks) aw3[ks] = wf[2560 + ks*64 + lane];
    f32x4 acc3[2];
    acc3[0] = (f32x4){0.f,0.f,0.f,0.f};
    acc3[1] = (f32x4){0.f,0.f,0.f,0.f};
    #pragma unroll
    for (int q = 0; q < 2; ++q)
        #pragma unroll
        for (int ks = 0; ks < 4; ++ks) {
            const bf16x8 hq3 = *(const bf16x8*)(smem + rb2[ks] + q*4096);
            acc3[q] = __builtin_amdgcn_mfma_f32_16x16x32_bf16(aw3[ks], hq3, acc3[q], 0, 0, 0);
        }

    // ---- sigmoid -> wave-private LDS staging -> coalesced store ----
    float* smf = (float*)slab;
    if (lk == 0) {
        const float b30 = g_b3[0], b31 = g_b3[1], b32 = g_b3[2];
        #pragma unroll
        for (int q = 0; q < 2; ++q) {
            const int o = (q*16 + lr)*3;
            smf[o + 0] = 1.0f / (1.0f + __expf(-(acc3[q][0] + b30)));
            smf[o + 1] = 1.0f / (1.0f + __expf(-(acc3[q][1] + b31)));
            smf[o + 2] = 1.0f / (1.0f + __expf(-(acc3[q][2] + b32)));
        }
    }
    asm volatile("s_waitcnt lgkmcnt(0)");
    __builtin_amdgcn_sched_barrier(0);
    {
        const int base = (ray*128 + wid*32)*3;
        out_rgb[base + lane] = smf[lane];
        if (lane < 32) out_rgb[base + 64 + lane] = smf[64 + lane];
    }
}

// ================= fallback prep (old layout) + fused kernel (v3) =================
__global__ __launch_bounds__(256)
void dvgo_prep_fb(const float* __restrict__ g_gd, const float* __restrict__ g_gc,
                  const float* __restrict__ g_w1, const float* __restrict__ g_w2,
                  const float* __restrict__ g_w3, const float* __restrict__ g_dir,
                  bf16x8* __restrict__ pack, __bf16* __restrict__ wsb, int wbase)
{
    const int bid = blockIdx.x;
    if (bid < wbase) {
        const int gi = bid * 256 + threadIdx.x;
        if (gi >= 1000000) return;
        bf16x8 v0, v1;
        #pragma unroll
        for (int c = 0; c < 8; ++c) v0[c] = (__bf16)g_gc[c * 1000000 + gi];
        #pragma unroll
        for (int c = 0; c < 4; ++c) v1[c] = (__bf16)g_gc[(8 + c) * 1000000 + gi];
        v1[4] = (__bf16)g_gd[gi];
        v1[5] = (__bf16)0.0f; v1[6] = (__bf16)0.0f; v1[7] = (__bf16)0.0f;
        pack[gi * 2 + 0] = v0;
        pack[gi * 2 + 1] = v1;
        return;
    }
    const int idx = (bid - wbase) * 256 + threadIdx.x;
    if (idx < 8192) {
        const int j = idx & 7, lane = (idx >> 3) & 63, ks = (idx >> 9) & 1, ct = idx >> 10;
        const int n = ct * 16 + (lane & 15);
        const int k = ks * 32 + ((lane >> 4) & 3) * 8 + j;
        wsb[idx] = (__bf16)((k < 39) ? g_w1[k * 128 + n] : 0.0f);
    } else if (idx < 24576) {
        const int i2 = idx - 8192;
        const int j = i2 & 7, lane = (i2 >> 3) & 63, ks = (i2 >> 9) & 3, ct = i2 >> 11;
        const int n = ct * 16 + (lane & 15);
        const int k = ks * 32 + ((lane >> 4) & 3) * 8 + j;
        wsb[idx] = (__bf16)g_w2[k * 128 + n];
    }
}

#define FB_FEAT_OFF 0
#define FB_PCC_OFF  16384
#define FB_H1_OFF   0
#define FB_PRGB_OFF 0

template <bool PACKED>
__global__ __launch_bounds__(256, 4)
void dvgo_main(const float* __restrict__ g_org, const float* __restrict__ g_dir,
               const float* __restrict__ g_len, const float* __restrict__ g_gd,
               const float* __restrict__ g_gc, const float* __restrict__ g_b1,
               const float* __restrict__ g_b2, const float* __restrict__ g_w3,
               const float* __restrict__ g_b3, const bf16x8* __restrict__ wf,
               const bf16x8* __restrict__ g_pack,
               float* __restrict__ out_alpha, float* __restrict__ out_rgb)
{
    __shared__ __align__(16) char smem[32768];
    float* smf = (float*)smem;
    const int tid = threadIdx.x;
    const int ray = blockIdx.x;
    const float d0 = g_dir[ray*3+0], d1 = g_dir[ray*3+1], d2 = g_dir[ray*3+2];
    {
        const float o0 = g_org[ray*3+0], o1 = g_org[ray*3+1], o2 = g_org[ray*3+2];
        const int p = tid & 127;
        const int dzv = tid >> 7;
        const float len = g_len[ray*128 + p];
        const float px = (o0 + d0*len + 1.0f) * 49.5f;
        const float py = (o1 + d1*len + 1.0f) * 49.5f;
        const float pz = (o2 + d2*len + 1.0f) * 49.5f;
        const float fx = floorf(px), fy = floorf(py), fz = floorf(pz);
        const int ix = (int)fx, iy = (int)fy, iz0 = (int)fz;
        const float qx = px - fx, qy = py - fy, qz = pz - fz;
        const float wxa[2] = {1.0f - qx, qx};
        const float wya[2] = {1.0f - qy, qy};
        const int  cxa[2] = {min(max(ix,0),99),   min(max(ix+1,0),99)};
        const int  cya[2] = {min(max(iy,0),99),   min(max(iy+1,0),99)};
        const bool vxa[2] = {(unsigned)ix < 100u, (unsigned)(ix+1) < 100u};
        const bool vya[2] = {(unsigned)iy < 100u, (unsigned)(iy+1) < 100u};
        const int  iz = iz0 + dzv;
        const float wz = dzv ? qz : (1.0f - qz);
        const int  cz = min(max(iz,0),99);
        const bool vz = (unsigned)iz < 100u;
        float den = 0.0f;
        float cc[12];
        #pragma unroll
        for (int c = 0; c < 12; ++c) cc[c] = 0.0f;
        #pragma unroll
        for (int dy = 0; dy < 2; ++dy)
        #pragma unroll
        for (int dx = 0; dx < 2; ++dx) {
            float w = wxa[dx] * wya[dy] * wz;
            if (!(vxa[dx] && vya[dy] && vz)) w = 0.0f;
            const int gi = (cz*100 + cya[dy])*100 + cxa[dx];
            if (PACKED) {
                const bf16x8 v0 = g_pack[gi*2 + 0];
                const bf16x8 v1 = g_pack[gi*2 + 1];
                #pragma unroll
                for (int c = 0; c < 8; ++c) cc[c]     += w * (float)v0[c];
                #pragma unroll
                for (int c = 0; c < 4; ++c) cc[8 + c] += w * (float)v1[c];
                den += w * (float)v1[4];
            } else {
                den += w * g_gd[gi];
                #pragma unroll
                for (int c = 0; c < 12; ++c) cc[c] += w * g_gc[c*1000000 + gi];
            }
        }
        if (dzv) {
            #pragma unroll
            for (int c = 0; c < 12; ++c) smf[FB_PCC_OFF/4 + p*13 + c] = cc[c];
            smf[FB_PCC_OFF/4 + p*13 + 12] = den;
        }
        __syncthreads();
        if (!dzv) {
            #pragma unroll
            for (int c = 0; c < 12; ++c) cc[c] += smf[FB_PCC_OFF/4 + p*13 + c];
            den += smf[FB_PCC_OFF/4 + p*13 + 12];
            const float interval = sqrtf(d0*d0 + d1*d1 + d2*d2);
            const float e = expf(den + ACT_SHIFT_F);
            out_alpha[ray*128 + p] = -expm1f(-interval * log1pf(e));
            bf16x8 f0; bf16x4 f1;
            #pragma unroll
            for (int c = 0; c < 8; ++c) f0[c] = (__bf16)cc[c];
            #pragma unroll
            for (int c = 0; c < 4; ++c) f1[c] = (__bf16)cc[8+c];
            const int swz = (p & 7) << 4;
            *reinterpret_cast<bf16x8*>(smem + ((FB_FEAT_OFF + p*128 +  0) ^ swz)) = f0;
            *reinterpret_cast<bf16x4*>(smem + ((FB_FEAT_OFF + p*128 + 16) ^ swz)) = f1;
        } else {
            float vals[52];
            vals[0] = d0; vals[1] = d1; vals[2] = d2;
            #pragma unroll
            for (int i = 0; i < 3; ++i) {
                const float di = (i == 0) ? d0 : ((i == 1) ? d1 : d2);
                #pragma unroll
                for (int j = 0; j < 4; ++j) {
                    const float a = di * (float)(1 << j);
                    vals[3  + i*4 + j] = sinf(a);
                    vals[15 + i*4 + j] = cosf(a);
                }
            }
            #pragma unroll
            for (int c = 27; c < 52; ++c) vals[c] = 0.0f;
            const int swz = (p & 7) << 4;
            #pragma unroll
            for (int i = 0; i < 13; ++i) {
                bf16x4 v4;
                #pragma unroll
                for (int r = 0; r < 4; ++r) v4[r] = (__bf16)vals[i*4 + r];
                *reinterpret_cast<bf16x4*>(smem + ((FB_FEAT_OFF + p*128 + 24 + i*8) ^ swz)) = v4;
            }
        }
    }
    __syncthreads();
    const int lane = tid & 63;
    const int wid  = tid >> 6;
    const int lr   = lane & 15;
    const int lk   = lane >> 4;
    {
        bf16x8 bf[2][2];
        #pragma unroll
        for (int rt = 0; rt < 2; ++rt)
            #pragma unroll
            for (int ks = 0; ks < 2; ++ks) {
                const int pt = wid*32 + rt*16 + lr;
                int a = FB_FEAT_OFF + pt*128 + ks*64 + lk*16; a ^= (pt & 7) << 4;
                bf[rt][ks] = *reinterpret_cast<const bf16x8*>(smem + a);
            }
        __syncthreads();
        f32x4 acc1[2][8];
        #pragma unroll
        for (int rt = 0; rt < 2; ++rt)
            #pragma unroll
            for (int ct = 0; ct < 8; ++ct) acc1[rt][ct] = (f32x4){0.f,0.f,0.f,0.f};
        #pragma unroll
        for (int ct = 0; ct < 8; ++ct) {
            const bf16x8 aw0 = wf[(ct*2 + 0)*64 + lane];
            const bf16x8 aw1 = wf[(ct*2 + 1)*64 + lane];
            #pragma unroll
            for (int rt = 0; rt < 2; ++rt) {
                acc1[rt][ct] = __builtin_amdgcn_mfma_f32_16x16x32_bf16(aw0, bf[rt][0], acc1[rt][ct], 0, 0, 0);
                acc1[rt][ct] = __builtin_amdgcn_mfma_f32_16x16x32_bf16(aw1, bf[rt][1], acc1[rt][ct], 0, 0, 0);
            }
        }
        #pragma unroll
        for (int ct = 0; ct < 8; ++ct) {
            const f32x4 b1v = *reinterpret_cast<const f32x4*>(g_b1 + ct*16 + lk*4);
            #pragma unroll
            for (int rt = 0; rt < 2; ++rt) {
                const int pt = wid*32 + rt*16 + lr;
                bf16x4 hv;
                #pragma unroll
                for (int r = 0; r < 4; ++r)
                    hv[r] = (__bf16)fmaxf(acc1[rt][ct][r] + b1v[r], 0.0f);
                int a = FB_H1_OFF + pt*256 + ct*32 + lk*8; a ^= (pt & 7) << 4;
                *reinterpret_cast<bf16x4*>(smem + a) = hv;
            }
        }
    }
    __syncthreads();
    const int wr = wid >> 1, wc = wid & 1;
    f32x4 acc2[4][4];
    #pragma unroll
    for (int rt = 0; rt < 4; ++rt)
        #pragma unroll
        for (int ct = 0; ct < 4; ++ct) acc2[rt][ct] = (f32x4){0.f,0.f,0.f,0.f};
    #pragma unroll
    for (int ks = 0; ks < 4; ++ks) {
        bf16x8 a2[4];
        #pragma unroll
        for (int rt = 0; rt < 4; ++rt) {
            const int pt = wr*64 + rt*16 + lr;
            int a = FB_H1_OFF + pt*256 + ks*64 + lk*16; a ^= (pt & 7) << 4;
            a2[rt] = *reinterpret_cast<const bf16x8*>(smem + a);
        }
        #pragma unroll
        for (int ct = 0; ct < 4; ++ct) {
            const int ctg = wc*4 + ct;
            const bf16x8 b2f = wf[1024 + (ctg*4 + ks)*64 + lane];
            #pragma unroll
            for (int rt = 0; rt < 4; ++rt)
                acc2[rt][ct] = __builtin_amdgcn_mfma_f32_16x16x32_bf16(a2[rt], b2f, acc2[rt][ct], 0, 0, 0);
        }
    }
    __syncthreads();
    {
        float b2v[4], w30[4], w31[4], w32[4];
        #pragma unroll
        for (int ct = 0; ct < 4; ++ct) {
            const int n2 = wc*64 + ct*16 + lr;
            b2v[ct] = g_b2[n2];
            w30[ct] = g_w3[n2*3 + 0];
            w31[ct] = g_w3[n2*3 + 1];
            w32[ct] = g_w3[n2*3 + 2];
        }
        #pragma unroll
        for (int rt = 0; rt < 4; ++rt)
            #pragma unroll
            for (int r = 0; r < 4; ++r) {
                float s0 = 0.f, s1 = 0.f, s2 = 0.f;
                #pragma unroll
                for (int ct = 0; ct < 4; ++ct) {
                    const float v = fmaxf(acc2[rt][ct][r] + b2v[ct], 0.0f);
                    s0 = fmaf(v, w30[ct], s0);
                    s1 = fmaf(v, w31[ct], s1);
                    s2 = fmaf(v, w32[ct], s2);
                }
                #pragma unroll
                for (int off = 1; off < 16; off <<= 1) {
                    s0 += __shfl_xor(s0, off);
                    s1 += __shfl_xor(s1, off);
                    s2 += __shfl_xor(s2, off);
                }
                if (lr == 0) {
                    const int pt = wr*64 + rt*16 + lk*4 + r;
                    const int base = FB_PRGB_OFF/4 + (wc*128 + pt)*3;
                    smf[base + 0] = s0;
                    smf[base + 1] = s1;
                    smf[base + 2] = s2;
                }
            }
    }
    __syncthreads();
    if (tid < 128) {
        const int p = tid;
        const float s0 = smf[p*3 + 0] + smf[(128 + p)*3 + 0] + g_b3[0];
        const float s1 = smf[p*3 + 1] + smf[(128 + p)*3 + 1] + g_b3[1];
        const float s2 = smf[p*3 + 2] + smf[(128 + p)*3 + 2] + g_b3[2];
        const int pt = ray*128 + p;
        out_rgb[pt*3 + 0] = 1.0f / (1.0f + expf(-s0));
        out_rgb[pt*3 + 1] = 1.0f / (1.0f + expf(-s1));
        out_rgb[pt*3 + 2] = 1.0f / (1.0f + expf(-s2));
    }
}

extern "C" void kernel_launch(void* const* d_in, const int* in_sizes, int n_in,
                              void* d_out, int out_size, void* d_ws, size_t ws_size,
                              hipStream_t stream)
{
    const float* g_org = (const float*)d_in[0];
    const float* g_dir = (const float*)d_in[1];
    const float* g_len = (const float*)d_in[2];
    const float* g_gd  = (const float*)d_in[3];
    const float* g_gc  = (const float*)d_in[4];
    const float* g_w1  = (const float*)d_in[5];
    const float* g_b1  = (const float*)d_in[6];
    const float* g_w2  = (const float*)d_in[7];
    const float* g_b2  = (const float*)d_in[8];
    const float* g_w3  = (const float*)d_in[9];
    const float* g_b3  = (const float*)d_in[10];
    float* out = (float*)d_out;

    if (ws_size >= NEED_FULL) {
        __bf16* wsb  = (__bf16*)d_ws;
        float*  b1r  = (float*)((char*)d_ws + B1R_B);
        bf16x8* pack = (bf16x8*)((char*)d_ws + PACK2_B);
        dvgo_prep2<<<6043, 256, 0, stream>>>(g_gd, g_gc, g_w1, g_w2, g_w3, g_dir,
                                             g_b1, pack, wsb, b1r);
        dvgo_mlp<<<4096, 256, 0, stream>>>((const bf16x8*)wsb, b1r, pack,
                                           g_org, g_dir, g_len,
                                           g_b2, g_b3, out, out + 4096*128);
    } else if (ws_size >= NEED_PACK) {
        __bf16* wsb  = (__bf16*)d_ws;
        bf16x8* pack = (bf16x8*)((char*)d_ws + EMB_B);
        dvgo_prep_fb<<<4011, 256, 0, stream>>>(g_gd, g_gc, g_w1, g_w2, g_w3, g_dir,
                                               pack, wsb, 3907);
        dvgo_main<true><<<4096, 256, 0, stream>>>(g_org, g_dir, g_len, g_gd, g_gc,
                                                  g_b1, g_b2, g_w3, g_b3,
                                                  (const bf16x8*)wsb, pack,
                                                  out, out + 4096*128);
    } else {
        __bf16* wsb = (__bf16*)d_ws;
        dvgo_prep_fb<<<104, 256, 0, stream>>>(g_gd, g_gc, g_w1, g_w2, g_w3, g_dir,
                                              (bf16x8*)d_ws, wsb, 0);
        dvgo_main<false><<<4096, 256, 0, stream>>>(g_org, g_dir, g_len, g_gd, g_gc,
                                                   g_b1, g_b2, g_w3, g_b3,
                                                   (const bf16x8*)wsb, nullptr,
                                                   out, out + 4096*128);
    }
}